// Round 15
// baseline (3945.018 us; speedup 1.0000x reference)
//
#include <hip/hip_runtime.h>
#include <math.h>

// Model dims
#define B_   32
#define S_   256
#define T_   20
#define H_   512
#define E_   300
#define C_   16
#define CE_  30
#define NF_  50
#define IN0_ 450      // E + 3*NF
#define KP0_ 480      // IN0 padded to %32
#define G4_  2048     // 4*H
#define NG_  4096     // 2 dirs * 4H

typedef __attribute__((ext_vector_type(8))) short bf16x8;
typedef __attribute__((ext_vector_type(4))) float f32x4;

__device__ __forceinline__ float sigm(float x) { return 1.f / (1.f + __expf(-x)); }
__device__ __forceinline__ float tanhfast(float x) {
  x = fminf(15.f, fmaxf(-15.f, x));
  float e = __expf(-2.f * x);
  return (1.f - e) / (1.f + e);
}
__device__ __forceinline__ unsigned short f2bf(float f) {
  unsigned int u = __float_as_uint(f);
  unsigned int r = (u + 0x7fffu + ((u >> 16) & 1u)) >> 16;
  return (unsigned short)r;
}
__device__ __forceinline__ float bf2f(unsigned int u) {
  return __uint_as_float(u << 16);
}

// direct global->LDS staging (16B/lane, wave-uniform LDS base + lane*16)
#define GLOAD_LDS(gp, lp)                                                    \
  __builtin_amdgcn_global_load_lds(                                          \
      (const __attribute__((address_space(1))) void*)(gp),                   \
      (__attribute__((address_space(3))) void*)(lp), 16, 0, 0)

// ---------------- Embedding + char CNN -> bf16 padded [8192][480] ----------------
__global__ __launch_bounds__(256) void embed_cnn(
    const int* __restrict__ x, const int* __restrict__ xc,
    const float* __restrict__ wemb, const float* __restrict__ cemb,
    const float* __restrict__ w2, const float* __restrict__ cb2,
    const float* __restrict__ w3, const float* __restrict__ cb3,
    const float* __restrict__ w4, const float* __restrict__ cb4,
    unsigned short* __restrict__ out) {
  int m = blockIdx.x;           // m = t*32 + b
  int t = m >> 5, b = m & 31;
  int tid = threadIdx.x;
  __shared__ float emb[C_][CE_];
  __shared__ float conv[2100];

  int wid = x[b * S_ + t];
  for (int e = tid; e < KP0_; e += 256) {
    if (e < E_) out[(size_t)m * KP0_ + e] = f2bf(wemb[(size_t)wid * E_ + e]);
    else if (e >= IN0_) out[(size_t)m * KP0_ + e] = 0;
  }

  for (int idx = tid; idx < C_ * CE_; idx += 256) {
    int c = idx / CE_, ce = idx % CE_;
    int cid = xc[(b * S_ + t) * C_ + c];
    emb[c][ce] = cemb[cid * CE_ + ce];
  }
  __syncthreads();

  for (int idx = tid; idx < 2100; idx += 256) {
    int kw, f, p;
    const float* w; const float* bb;
    int r = idx;
    if (r < 750)      { kw = 2; f = r / 15; p = r % 15; w = w2; bb = cb2; }
    else if (r < 1450){ r -= 750;  kw = 3; f = r / 14; p = r % 14; w = w3; bb = cb3; }
    else              { r -= 1450; kw = 4; f = r / 13; p = r % 13; w = w4; bb = cb4; }
    float acc = bb[f];
    for (int j = 0; j < kw; ++j)
      for (int ce = 0; ce < CE_; ++ce)
        acc = fmaf(emb[p + j][ce], w[(f * CE_ + ce) * kw + j], acc);
    conv[idx] = fmaxf(acc, 0.f);
  }
  __syncthreads();

  if (tid < 150) {
    int kk = tid / 50, f = tid % 50;
    int base, np;
    if (kk == 0)      { base = f * 15;        np = 15; }
    else if (kk == 1) { base = 750 + f * 14;  np = 14; }
    else              { base = 1450 + f * 13; np = 13; }
    float mx = 0.f;
    for (int p = 0; p < np; ++p) mx = fmaxf(mx, conv[base + p]);
    out[(size_t)m * KP0_ + E_ + kk * 50 + f] = f2bf(mx);
  }
}

// ---------------- fp32 -> bf16 cast with K padding ----------------
__global__ __launch_bounds__(256) void castpad(
    const float* __restrict__ src, unsigned short* __restrict__ dst,
    int R, int K, int Kp) {
  int i = blockIdx.x * 256 + threadIdx.x;
  if (i < R * Kp) {
    int r = i / Kp, k = i - r * Kp;
    dst[i] = (k < K) ? f2bf(src[(size_t)r * K + k]) : (unsigned short)0;
  }
}

// ---------------- bf16 MFMA GEMM (global_load_lds staging): C = A @ W^T + b1 + b2 ----------------
__global__ __launch_bounds__(256) void gemm_bf16(
    const unsigned short* __restrict__ A, const unsigned short* __restrict__ W,
    const float* __restrict__ bias1, const float* __restrict__ bias2,
    float* __restrict__ C, int M, int N, int Kp) {
  __shared__ unsigned short As[128][32];   // linear: row = 64B (required by gload_lds)
  __shared__ unsigned short Bs[128][32];
  int bm = blockIdx.y * 128, bn = blockIdx.x * 128;
  int tid = threadIdx.x;
  int wave = tid >> 6, lane = tid & 63;
  int wm = (wave & 1) * 64, wn = (wave >> 1) * 64;
  int l15 = lane & 15, l4 = lane >> 4;

  int srow = lane >> 2;
  int scol = (lane & 3) * 8;
  const unsigned short* ga0 = A + (size_t)(bm + wave * 32 + srow) * Kp + scol;
  const unsigned short* ga1 = A + (size_t)(bm + wave * 32 + 16 + srow) * Kp + scol;
  const unsigned short* gb0 = W + (size_t)(bn + wave * 32 + srow) * Kp + scol;
  const unsigned short* gb1 = W + (size_t)(bn + wave * 32 + 16 + srow) * Kp + scol;

  f32x4 acc[4][4];
#pragma unroll
  for (int i = 0; i < 4; ++i)
#pragma unroll
    for (int j = 0; j < 4; ++j) acc[i][j] = (f32x4){0.f, 0.f, 0.f, 0.f};

  for (int k0 = 0; k0 < Kp; k0 += 32) {
    __syncthreads();
    GLOAD_LDS(ga0 + k0, &As[wave * 32][0]);
    GLOAD_LDS(ga1 + k0, &As[wave * 32 + 16][0]);
    GLOAD_LDS(gb0 + k0, &Bs[wave * 32][0]);
    GLOAD_LDS(gb1 + k0, &Bs[wave * 32 + 16][0]);
    __syncthreads();

    bf16x8 af[4], bfv[4];
#pragma unroll
    for (int i = 0; i < 4; ++i) af[i]  = *(const bf16x8*)&As[wm + i * 16 + l15][l4 * 8];
#pragma unroll
    for (int j = 0; j < 4; ++j) bfv[j] = *(const bf16x8*)&Bs[wn + j * 16 + l15][l4 * 8];
#pragma unroll
    for (int i = 0; i < 4; ++i)
#pragma unroll
      for (int j = 0; j < 4; ++j)
        acc[i][j] = __builtin_amdgcn_mfma_f32_16x16x32_bf16(af[i], bfv[j], acc[i][j], 0, 0, 0);
  }

#pragma unroll
  for (int j = 0; j < 4; ++j) {
    int gn = bn + wn + j * 16 + l15;
    float bsum = (bias1 ? bias1[gn] : 0.f) + (bias2 ? bias2[gn] : 0.f);
#pragma unroll
    for (int i = 0; i < 4; ++i) {
#pragma unroll
      for (int r = 0; r < 4; ++r) {
        int gm = bm + wm + i * 16 + l4 * 4 + r;
        C[(size_t)gm * N + gn] = acc[i][j][r] + bsum;
      }
    }
  }
}

// ---------------- Persistent BiLSTM scan: fused gates-in-lane ----------------
// 32 WGs: dir = wg>>4, hb = wg&15 (32 hidden units each). 512 threads = 8 waves.
// Wave w's MFMA A-rows: row r <-> (hh = r>>2, g = r&3), hh in [w*4, w*4+4).
// C-layout (col=lane&15, row=(lane>>4)*4+reg) then puts ALL 4 GATES of cell
// (hidden hbase+w*4+l4, batch l15 / l15+16) into one lane's acc -> pointwise
// fuses onto the accumulator: no lds_g, no gate-exchange barriers, pointwise
// parallel across all 8 waves. h-pair packing via __shfl_xor(.,16) (partner
// lane holds hidx^1). Exchange/flag protocol identical to proven r12.
__global__ __launch_bounds__(512, 1) void lstm_scan(
    const float* __restrict__ P,          // [8192][4096] x-proj + biases
    const float* __restrict__ whh,        // [2][2048][512]
    unsigned int* __restrict__ Hbf32,     // [8192][512] u32 = bf16 pairs
    unsigned int* __restrict__ hT,        // [2 parity][2 dir][32 b][256 u32]
    int* __restrict__ flags) {            // [2 dirs][32] (16 used per dir)
  int wg  = blockIdx.x;          // 0..31
  int dir = wg >> 4;
  int hb  = wg & 15;
  int hbase = hb * 32;
  int tid = threadIdx.x;
  int wave = tid >> 6;
  int lane = tid & 63;
  int l15 = lane & 15;
  int l4  = lane >> 4;
  int hidx = hbase + wave * 4 + l4;       // this lane's hidden unit

  // resident weight A-fragments: row l15 <-> (hh=l15>>2, g=l15&3)
  int arow_h = hbase + wave * 4 + (l15 >> 2);
  int arow_g = l15 & 3;
  const float* wrow = whh + ((size_t)dir * G4_ + arow_g * H_ + arow_h) * H_;
  bf16x8 afrag[16];
#pragma unroll
  for (int kk = 0; kk < 16; ++kk) {
    int k0 = kk * 32 + l4 * 8;
    float4 lo = *(const float4*)(wrow + k0);
    float4 hi = *(const float4*)(wrow + k0 + 4);
    bf16x8 a;
    a[0] = (short)f2bf(lo.x); a[1] = (short)f2bf(lo.y);
    a[2] = (short)f2bf(lo.z); a[3] = (short)f2bf(lo.w);
    a[4] = (short)f2bf(hi.x); a[5] = (short)f2bf(hi.y);
    a[6] = (short)f2bf(hi.z); a[7] = (short)f2bf(hi.w);
    afrag[kk] = a;
  }

  __shared__ unsigned short hlds[32][520];   // 1040B row stride
  int* dflags = flags + dir * 32;

  float c0 = 0.f, c1 = 0.f;                  // cell state: batch l15, l15+16
  float pfc0[4], pfc1[4], pfn0[4], pfn1[4];  // P per gate, two batches

  {
    int t0i = dir ? (S_ - 1) : 0;
    size_t pr0 = ((size_t)(t0i * B_ + l15)) * NG_ + (size_t)dir * G4_ + hidx;
    size_t pr1 = ((size_t)(t0i * B_ + 16 + l15)) * NG_ + (size_t)dir * G4_ + hidx;
#pragma unroll
    for (int gg = 0; gg < 4; ++gg) {
      pfc0[gg] = P[pr0 + gg * H_];
      pfc1[gg] = P[pr1 + gg * H_];
    }
  }

  // staging mapping: lane stages row (wave*4 + (lane&3)), 64B chunk (lane>>2)
  int srow   = wave * 4 + (lane & 3);
  int schunk = lane >> 2;
  const unsigned short* slabBase = (const unsigned short*)hT + (size_t)dir * (32 * 512);

  for (int s = 0; s < S_; ++s) {
    int t = dir ? (S_ - 1 - s) : s;

    f32x4 acc0 = {0.f, 0.f, 0.f, 0.f};
    f32x4 acc1 = {0.f, 0.f, 0.f, 0.f};
    if (s > 0) {
      const unsigned short* src = slabBase + (size_t)((s + 1) & 1) * (2 * 32 * 512)
                                  + srow * 512 + schunk * 32;
      bf16x8 t0, t1, t2, t3;
      asm volatile("global_load_dwordx4 %0, %1, off sc0 sc1"           : "=v"(t0) : "v"(src) : "memory");
      asm volatile("global_load_dwordx4 %0, %1, off offset:16 sc0 sc1" : "=v"(t1) : "v"(src) : "memory");
      asm volatile("global_load_dwordx4 %0, %1, off offset:32 sc0 sc1" : "=v"(t2) : "v"(src) : "memory");
      asm volatile("global_load_dwordx4 %0, %1, off offset:48 sc0 sc1" : "=v"(t3) : "v"(src) : "memory");
      // prefetch next step's P while stage loads are in flight; then wait for
      // the STAGE loads only (8 younger P loads stay outstanding).
      if (s < S_ - 1) {
        int tn = dir ? (S_ - 2 - s) : (s + 1);
        size_t pr0 = ((size_t)(tn * B_ + l15)) * NG_ + (size_t)dir * G4_ + hidx;
        size_t pr1 = ((size_t)(tn * B_ + 16 + l15)) * NG_ + (size_t)dir * G4_ + hidx;
#pragma unroll
        for (int gg = 0; gg < 4; ++gg) {
          pfn0[gg] = P[pr0 + gg * H_];
          pfn1[gg] = P[pr1 + gg * H_];
        }
        asm volatile("s_waitcnt vmcnt(8)" ::: "memory");
      } else {
        asm volatile("s_waitcnt vmcnt(0)" ::: "memory");
      }
      __builtin_amdgcn_sched_barrier(0);
      *(bf16x8*)&hlds[srow][schunk * 32 +  0] = t0;
      *(bf16x8*)&hlds[srow][schunk * 32 +  8] = t1;
      *(bf16x8*)&hlds[srow][schunk * 32 + 16] = t2;
      *(bf16x8*)&hlds[srow][schunk * 32 + 24] = t3;
      __syncthreads();   // stage visible to all waves

#pragma unroll
      for (int kk = 0; kk < 16; ++kk) {
        bf16x8 b0 = *(const bf16x8*)&hlds[l15][kk * 32 + l4 * 8];
        bf16x8 b1 = *(const bf16x8*)&hlds[16 + l15][kk * 32 + l4 * 8];
        acc0 = __builtin_amdgcn_mfma_f32_16x16x32_bf16(afrag[kk], b0, acc0, 0, 0, 0);
        acc1 = __builtin_amdgcn_mfma_f32_16x16x32_bf16(afrag[kk], b1, acc1, 0, 0, 0);
      }
    } else {
      // prefetch for step 1
      int tn = dir ? (S_ - 2) : 1;
      size_t pr0 = ((size_t)(tn * B_ + l15)) * NG_ + (size_t)dir * G4_ + hidx;
      size_t pr1 = ((size_t)(tn * B_ + 16 + l15)) * NG_ + (size_t)dir * G4_ + hidx;
#pragma unroll
      for (int gg = 0; gg < 4; ++gg) {
        pfn0[gg] = P[pr0 + gg * H_];
        pfn1[gg] = P[pr1 + gg * H_];
      }
    }

    // pointwise, fully in-lane (all 8 waves): acc reg r = gate r (i,f,g,o)
    {
      float iv0 = acc0[0] + pfc0[0], fv0 = acc0[1] + pfc0[1];
      float gv0 = acc0[2] + pfc0[2], ov0 = acc0[3] + pfc0[3];
      float iv1 = acc1[0] + pfc1[0], fv1 = acc1[1] + pfc1[1];
      float gv1 = acc1[2] + pfc1[2], ov1 = acc1[3] + pfc1[3];
      c0 = sigm(fv0) * c0 + sigm(iv0) * tanhfast(gv0);
      c1 = sigm(fv1) * c1 + sigm(iv1) * tanhfast(gv1);
      float hn0 = sigm(ov0) * tanhfast(c0);
      float hn1 = sigm(ov1) * tanhfast(c1);
      // pack hidden pair (hidx even | hidx+1 from lane^16) into u32
      unsigned int m0 = (unsigned int)f2bf(hn0);
      unsigned int m1 = (unsigned int)f2bf(hn1);
      unsigned int p0 = (unsigned int)__shfl_xor((int)m0, 16);
      unsigned int p1 = (unsigned int)__shfl_xor((int)m1, 16);
      if ((l4 & 1) == 0) {
        unsigned int w0 = m0 | (p0 << 16);
        unsigned int w1 = m1 | (p1 << 16);
        int hw = hidx >> 1;
        Hbf32[((size_t)(t * B_ + l15)) * 512 + dir * 256 + hw] = w0;
        Hbf32[((size_t)(t * B_ + 16 + l15)) * 512 + dir * 256 + hw] = w1;
        unsigned int* hc = hT + (((size_t)(s & 1) * 2 + dir) * 32) * 256;
        __hip_atomic_store(hc + (size_t)l15 * 256 + hw,        w0, __ATOMIC_RELAXED, __HIP_MEMORY_SCOPE_AGENT);
        __hip_atomic_store(hc + (size_t)(16 + l15) * 256 + hw, w1, __ATOMIC_RELAXED, __HIP_MEMORY_SCOPE_AGENT);
      }
      // rotate P double-buffer
#pragma unroll
      for (int gg = 0; gg < 4; ++gg) { pfc0[gg] = pfn0[gg]; pfc1[gg] = pfn1[gg]; }
    }

    if (s < S_ - 1) {
      __syncthreads();   // drains vmcnt per wave: all hT stores at LLC
      if (wave == 0) {
        int target = s + 1;
        if (lane == 0)
          __hip_atomic_store(dflags + hb, target, __ATOMIC_RELAXED, __HIP_MEMORY_SCOPE_AGENT);
        int guard = 0;
        for (;;) {
          int v = target;
          if (lane < 16)
            v = __hip_atomic_load(dflags + lane, __ATOMIC_RELAXED, __HIP_MEMORY_SCOPE_AGENT);
          if (__all(v >= target)) break;
          __builtin_amdgcn_s_sleep(1);
          if (++guard > (1 << 17)) break;   // safety valve: wrong answer, not a hang
        }
      }
      __syncthreads();
      // no fence: readers bypass caches (sc0 sc1); caches stay hot for P/weights
    }
  }
}

// ---------------- fused highway + FC logits (one row per block) ----------------
__global__ __launch_bounds__(256) void hwfc_k(
    const unsigned int* __restrict__ Xbf,  // [8192][512] bf16 pairs (LSTM out)
    const float* __restrict__ G1,          // [8192][1024] T-gate pre-act
    const float* __restrict__ G2,          // [8192][1024] H pre-act
    const float* __restrict__ fc_w,        // [20][1024]
    const float* __restrict__ fc_b,        // [20]
    float* __restrict__ LOG) {             // [8192][20]
  int m = blockIdx.x;
  int tid = threadIdx.x;
  int wave = tid >> 6, lane = tid & 63;
  int e0 = tid * 4;

  unsigned int xv0 = Xbf[(size_t)m * 512 + tid * 2];
  unsigned int xv1 = Xbf[(size_t)m * 512 + tid * 2 + 1];
  float4 g1 = *(const float4*)(G1 + (size_t)m * 1024 + e0);
  float4 g2 = *(const float4*)(G2 + (size_t)m * 1024 + e0);
  float tg, o[4];
  tg = sigm(g1.x); o[0] = tg * fmaxf(g2.x, 0.f) + (1.f - tg) * bf2f(xv0 & 0xffffu);
  tg = sigm(g1.y); o[1] = tg * fmaxf(g2.y, 0.f) + (1.f - tg) * bf2f(xv0 >> 16);
  tg = sigm(g1.z); o[2] = tg * fmaxf(g2.z, 0.f) + (1.f - tg) * bf2f(xv1 & 0xffffu);
  tg = sigm(g1.w); o[3] = tg * fmaxf(g2.w, 0.f) + (1.f - tg) * bf2f(xv1 >> 16);

  float acc[T_];
#pragma unroll
  for (int j = 0; j < T_; ++j) {
    float4 w = *(const float4*)(fc_w + (size_t)j * 1024 + e0);
    acc[j] = o[0] * w.x + o[1] * w.y + o[2] * w.z + o[3] * w.w;
  }
#pragma unroll
  for (int off = 32; off > 0; off >>= 1)
#pragma unroll
    for (int j = 0; j < T_; ++j)
      acc[j] += __shfl_xor(acc[j], off);

  __shared__ float part[4][T_];
  if (lane == 0)
#pragma unroll
    for (int j = 0; j < T_; ++j) part[wave][j] = acc[j];
  __syncthreads();
  if (tid < T_)
    LOG[(size_t)m * T_ + tid] =
        part[0][tid] + part[1][tid] + part[2][tid] + part[3][tid] + fc_b[tid];
}

// ---------------- CRF gold score (parallel reduction over t) ----------------
__global__ __launch_bounds__(256) void crf_score_k(
    const int* __restrict__ x, const int* __restrict__ tags,
    const float* __restrict__ L,
    const float* __restrict__ cstart, const float* __restrict__ cend,
    const float* __restrict__ ctrans, float* __restrict__ score) {
  int b = blockIdx.x;
  int t = threadIdx.x;                   // S_ == 256 == blockDim
  int tg = tags[b * S_ + t];
  float part = 0.f;
  bool valid;
  if (t == 0) {
    part = cstart[tg] + L[(size_t)b * T_ + tg];
    valid = true;
  } else {
    valid = (x[b * S_ + t] != 0);
    if (valid)
      part = ctrans[tags[b * S_ + t - 1] * T_ + tg] + L[((size_t)t * B_ + b) * T_ + tg];
  }
  bool nextInvalid = (t == S_ - 1) || (x[b * S_ + t + 1] == 0);
  if (valid && nextInvalid) part += cend[tg];

  __shared__ float red[256];
  red[t] = part;
  __syncthreads();
  for (int off = 128; off > 0; off >>= 1) {
    if (t < off) red[t] += red[t + off];
    __syncthreads();
  }
  if (t == 0) score[b] = red[0];
}

// ---------------- CRF forward (log partition), one block per batch ----------------
__global__ __launch_bounds__(64) void crf_forward_k(
    const int* __restrict__ x, const float* __restrict__ L,
    const float* __restrict__ cstart, const float* __restrict__ cend,
    const float* __restrict__ ctrans, float* __restrict__ logz) {
  int b = blockIdx.x;
  int tp = threadIdx.x;
  __shared__ float alpha[T_];
  __shared__ float trT[T_][T_];
  for (int i = tp; i < T_ * T_; i += 64)
    trT[i / T_][i % T_] = ctrans[(i % T_) * T_ + (i / T_)];
  if (tp < T_) alpha[tp] = cstart[tp] + L[(size_t)b * T_ + tp];
  __syncthreads();
  for (int t = 1; t < S_; ++t) {
    float newv = 0.f;
    bool active = tp < T_;
    bool msk = x[b * S_ + t] != 0;
    if (active) {
      float em = L[((size_t)t * B_ + b) * T_ + tp];
      float mx = -1e30f;
#pragma unroll
      for (int tt = 0; tt < T_; ++tt) mx = fmaxf(mx, alpha[tt] + trT[tp][tt]);
      float sum = 0.f;
#pragma unroll
      for (int tt = 0; tt < T_; ++tt) sum += __expf(alpha[tt] + trT[tp][tt] - mx);
      float nxt = mx + __logf(sum) + em;
      newv = msk ? nxt : alpha[tp];
    }
    __syncthreads();
    if (active) alpha[tp] = newv;
    __syncthreads();
  }
  if (tp == 0) {
    float mx = -1e30f;
    for (int tt = 0; tt < T_; ++tt) mx = fmaxf(mx, alpha[tt] + cend[tt]);
    float sum = 0.f;
    for (int tt = 0; tt < T_; ++tt) sum += __expf(alpha[tt] + cend[tt] - mx);
    logz[b] = mx + __logf(sum);
  }
}

// ---------------- token NLL (aux loss) ----------------
__global__ __launch_bounds__(256) void nll_k(const float* __restrict__ L,
                                             const int* __restrict__ tags,
                                             float* __restrict__ accum) {
  int m = blockIdx.x * 256 + threadIdx.x;
  float nv = 0.f, vv = 0.f;
  if (m < B_ * S_) {
    int t = m >> 5, b = m & 31;
    int tg = tags[b * S_ + t];
    const float* row = L + (size_t)m * T_;
    float mx = -1e30f;
    for (int i = 0; i < T_; ++i) mx = fmaxf(mx, row[i]);
    float sum = 0.f;
    for (int i = 0; i < T_; ++i) sum += expf(row[i] - mx);
    float lse = mx + logf(sum);
    if (tg != 0) { nv = lse - row[tg]; vv = 1.f; }
  }
  __shared__ float sn[256], sv[256];
  int tid = threadIdx.x;
  sn[tid] = nv; sv[tid] = vv;
  __syncthreads();
  for (int off = 128; off > 0; off >>= 1) {
    if (tid < off) { sn[tid] += sn[tid + off]; sv[tid] += sv[tid + off]; }
    __syncthreads();
  }
  if (tid == 0) { atomicAdd(&accum[0], sn[0]); atomicAdd(&accum[1], sv[0]); }
}

// ---------------- final scalar ----------------
__global__ void final_k(const float* __restrict__ score, const float* __restrict__ logz,
                        const float* __restrict__ accum, float* __restrict__ out) {
  if (threadIdx.x == 0 && blockIdx.x == 0) {
    float s = 0.f;
    for (int b = 0; b < B_; ++b) s += score[b] - logz[b];
    float crf = -s / (float)B_;
    out[0] = crf + 0.1f * (accum[0] / accum[1]);
  }
}

extern "C" void kernel_launch(void* const* d_in, const int* in_sizes, int n_in,
                              void* d_out, int out_size, void* d_ws, size_t ws_size,
                              hipStream_t stream) {
  (void)in_sizes; (void)n_in; (void)out_size; (void)ws_size;
  const int*   x      = (const int*)d_in[0];
  const int*   xc     = (const int*)d_in[1];
  const int*   tags   = (const int*)d_in[2];
  const float* wemb   = (const float*)d_in[3];
  const float* cemb   = (const float*)d_in[4];
  const float* w2     = (const float*)d_in[5];
  const float* cb2    = (const float*)d_in[6];
  const float* w3     = (const float*)d_in[7];
  const float* cb3    = (const float*)d_in[8];
  const float* w4     = (const float*)d_in[9];
  const float* cb4    = (const float*)d_in[10];
  const float* l0_wih = (const float*)d_in[11];
  const float* l0_whh = (const float*)d_in[12];
  const float* l0_bih = (const float*)d_in[13];
  const float* l0_bhh = (const float*)d_in[14];
  const float* l1_wih = (const float*)d_in[15];
  const float* l1_whh = (const float*)d_in[16];
  const float* l1_bih = (const float*)d_in[17];
  const float* l1_bhh = (const float*)d_in[18];
  const float* hw_Hw  = (const float*)d_in[19];
  const float* hw_Hb  = (const float*)d_in[20];
  const float* hw_Tw  = (const float*)d_in[21];
  const float* hw_Tb  = (const float*)d_in[22];
  const float* fc_w   = (const float*)d_in[23];
  const float* fc_b   = (const float*)d_in[24];
  const float* cstart = (const float*)d_in[25];
  const float* cend   = (const float*)d_in[26];
  const float* ctrans = (const float*)d_in[27];

  // workspace layout (float units), total ~42.01M floats ~= 168 MB
  float* ws    = (float*)d_ws;
  float* P     = ws;                              // [0, 33554432)
  float* G1    = P;                               // aliases into P (dead after scans)
  float* G2    = P + 8388608;
  unsigned short* Hbf    = (unsigned short*)(ws + 33554432);   // 8192*1024 bf16
  unsigned short* COMBbf = (unsigned short*)(ws + 37748736);   // 8192*480 bf16
  unsigned short* Wbf    = (unsigned short*)(ws + 39714816);   // 4096*1024 bf16
  float* LOG   = ws + 41811968;                   // 163,840
  unsigned int* hT = (unsigned int*)(ws + 41975808);  // 32,768 u32
  int*   flags = (int*)(ws + 42008576);           // 128 ints
  float* score = ws + 42008576 + 128;
  float* logz  = score + 32;
  float* accum = logz + 32;

  hipMemsetAsync(accum, 0, 2 * sizeof(float), stream);

  // 1. embedding + char CNN -> bf16 padded
  embed_cnn<<<B_ * S_, 256, 0, stream>>>(x, xc, wemb, cemb, w2, cb2, w3, cb3, w4, cb4, COMBbf);

  // 2. layer0 input projection (bf16 MFMA)
  castpad<<<(4096 * KP0_ + 255) / 256, 256, 0, stream>>>(l0_wih, Wbf, 4096, IN0_, KP0_);
  {
    dim3 g(NG_ / 128, (B_ * S_) / 128);
    gemm_bf16<<<g, 256, 0, stream>>>(COMBbf, Wbf, l0_bih, l0_bhh, P, B_ * S_, NG_, KP0_);
  }
  // 3. layer0 recurrence (32 WGs, fused-gates scan)
  hipMemsetAsync(flags, 0, 128 * sizeof(int), stream);
  lstm_scan<<<32, 512, 0, stream>>>(P, l0_whh, (unsigned int*)Hbf, hT, flags);

  // 4. layer1 input projection
  castpad<<<(4096 * 1024 + 255) / 256, 256, 0, stream>>>(l1_wih, Wbf, 4096, 1024, 1024);
  {
    dim3 g(NG_ / 128, (B_ * S_) / 128);
    gemm_bf16<<<g, 256, 0, stream>>>(Hbf, Wbf, l1_bih, l1_bhh, P, B_ * S_, NG_, 1024);
  }
  // 5. layer1 recurrence
  hipMemsetAsync(flags, 0, 128 * sizeof(int), stream);
  lstm_scan<<<32, 512, 0, stream>>>(P, l1_whh, (unsigned int*)Hbf, hT, flags);

  // 6. highway gate GEMMs (bf16 MFMA)
  {
    dim3 g(1024 / 128, (B_ * S_) / 128);
    castpad<<<(1024 * 1024 + 255) / 256, 256, 0, stream>>>(hw_Tw, Wbf, 1024, 1024, 1024);
    gemm_bf16<<<g, 256, 0, stream>>>(Hbf, Wbf, hw_Tb, nullptr, G1, B_ * S_, 1024, 1024);
    castpad<<<(1024 * 1024 + 255) / 256, 256, 0, stream>>>(hw_Hw, Wbf, 1024, 1024, 1024);
    gemm_bf16<<<g, 256, 0, stream>>>(Hbf, Wbf, hw_Hb, nullptr, G2, B_ * S_, 1024, 1024);
  }
  // 7. fused highway combine + fc logits
  hwfc_k<<<B_ * S_, 256, 0, stream>>>(
      (const unsigned int*)Hbf, G1, G2, fc_w, fc_b, LOG);

  // 8. CRF + losses
  crf_score_k<<<B_, 256, 0, stream>>>(x, tags, LOG, cstart, cend, ctrans, score);
  crf_forward_k<<<B_, 64, 0, stream>>>(x, LOG, cstart, cend, ctrans, logz);
  nll_k<<<(B_ * S_ + 255) / 256, 256, 0, stream>>>(LOG, tags, accum);
  final_k<<<1, 64, 0, stream>>>(score, logz, accum, (float*)d_out);
}

// Round 16
// 3395.602 us; speedup vs baseline: 1.1618x; 1.1618x over previous
//
#include <hip/hip_runtime.h>
#include <math.h>

// Model dims
#define B_   32
#define S_   256
#define T_   20
#define H_   512
#define E_   300
#define C_   16
#define CE_  30
#define NF_  50
#define IN0_ 450      // E + 3*NF
#define KP0_ 480      // IN0 padded to %32
#define G4_  2048     // 4*H
#define NG_  4096     // 2 dirs * 4H

typedef __attribute__((ext_vector_type(8))) short bf16x8;
typedef __attribute__((ext_vector_type(4))) float f32x4;

__device__ __forceinline__ float sigm(float x) { return 1.f / (1.f + __expf(-x)); }
__device__ __forceinline__ float tanhfast(float x) {
  x = fminf(15.f, fmaxf(-15.f, x));
  float e = __expf(-2.f * x);
  return (1.f - e) / (1.f + e);
}
__device__ __forceinline__ unsigned short f2bf(float f) {
  unsigned int u = __float_as_uint(f);
  unsigned int r = (u + 0x7fffu + ((u >> 16) & 1u)) >> 16;
  return (unsigned short)r;
}
__device__ __forceinline__ float bf2f(unsigned int u) {
  return __uint_as_float(u << 16);
}

// direct global->LDS staging (16B/lane, wave-uniform LDS base + lane*16)
#define GLOAD_LDS(gp, lp)                                                    \
  __builtin_amdgcn_global_load_lds(                                          \
      (const __attribute__((address_space(1))) void*)(gp),                   \
      (__attribute__((address_space(3))) void*)(lp), 16, 0, 0)

// ---------------- Embedding + char CNN -> bf16 padded [8192][480] ----------------
__global__ __launch_bounds__(256) void embed_cnn(
    const int* __restrict__ x, const int* __restrict__ xc,
    const float* __restrict__ wemb, const float* __restrict__ cemb,
    const float* __restrict__ w2, const float* __restrict__ cb2,
    const float* __restrict__ w3, const float* __restrict__ cb3,
    const float* __restrict__ w4, const float* __restrict__ cb4,
    unsigned short* __restrict__ out) {
  int m = blockIdx.x;           // m = t*32 + b
  int t = m >> 5, b = m & 31;
  int tid = threadIdx.x;
  __shared__ float emb[C_][CE_];
  __shared__ float conv[2100];

  int wid = x[b * S_ + t];
  for (int e = tid; e < KP0_; e += 256) {
    if (e < E_) out[(size_t)m * KP0_ + e] = f2bf(wemb[(size_t)wid * E_ + e]);
    else if (e >= IN0_) out[(size_t)m * KP0_ + e] = 0;
  }

  for (int idx = tid; idx < C_ * CE_; idx += 256) {
    int c = idx / CE_, ce = idx % CE_;
    int cid = xc[(b * S_ + t) * C_ + c];
    emb[c][ce] = cemb[cid * CE_ + ce];
  }
  __syncthreads();

  for (int idx = tid; idx < 2100; idx += 256) {
    int kw, f, p;
    const float* w; const float* bb;
    int r = idx;
    if (r < 750)      { kw = 2; f = r / 15; p = r % 15; w = w2; bb = cb2; }
    else if (r < 1450){ r -= 750;  kw = 3; f = r / 14; p = r % 14; w = w3; bb = cb3; }
    else              { r -= 1450; kw = 4; f = r / 13; p = r % 13; w = w4; bb = cb4; }
    float acc = bb[f];
    for (int j = 0; j < kw; ++j)
      for (int ce = 0; ce < CE_; ++ce)
        acc = fmaf(emb[p + j][ce], w[(f * CE_ + ce) * kw + j], acc);
    conv[idx] = fmaxf(acc, 0.f);
  }
  __syncthreads();

  if (tid < 150) {
    int kk = tid / 50, f = tid % 50;
    int base, np;
    if (kk == 0)      { base = f * 15;        np = 15; }
    else if (kk == 1) { base = 750 + f * 14;  np = 14; }
    else              { base = 1450 + f * 13; np = 13; }
    float mx = 0.f;
    for (int p = 0; p < np; ++p) mx = fmaxf(mx, conv[base + p]);
    out[(size_t)m * KP0_ + E_ + kk * 50 + f] = f2bf(mx);
  }
}

// ---------------- fp32 -> bf16 cast with K padding ----------------
__global__ __launch_bounds__(256) void castpad(
    const float* __restrict__ src, unsigned short* __restrict__ dst,
    int R, int K, int Kp) {
  int i = blockIdx.x * 256 + threadIdx.x;
  if (i < R * Kp) {
    int r = i / Kp, k = i - r * Kp;
    dst[i] = (k < K) ? f2bf(src[(size_t)r * K + k]) : (unsigned short)0;
  }
}

// ---------------- bf16 MFMA GEMM (global_load_lds staging): C = A @ W^T + b1 + b2 ----------------
__global__ __launch_bounds__(256) void gemm_bf16(
    const unsigned short* __restrict__ A, const unsigned short* __restrict__ W,
    const float* __restrict__ bias1, const float* __restrict__ bias2,
    float* __restrict__ C, int M, int N, int Kp) {
  __shared__ unsigned short As[128][32];   // linear: row = 64B (required by gload_lds)
  __shared__ unsigned short Bs[128][32];
  int bm = blockIdx.y * 128, bn = blockIdx.x * 128;
  int tid = threadIdx.x;
  int wave = tid >> 6, lane = tid & 63;
  int wm = (wave & 1) * 64, wn = (wave >> 1) * 64;
  int l15 = lane & 15, l4 = lane >> 4;

  int srow = lane >> 2;
  int scol = (lane & 3) * 8;
  const unsigned short* ga0 = A + (size_t)(bm + wave * 32 + srow) * Kp + scol;
  const unsigned short* ga1 = A + (size_t)(bm + wave * 32 + 16 + srow) * Kp + scol;
  const unsigned short* gb0 = W + (size_t)(bn + wave * 32 + srow) * Kp + scol;
  const unsigned short* gb1 = W + (size_t)(bn + wave * 32 + 16 + srow) * Kp + scol;

  f32x4 acc[4][4];
#pragma unroll
  for (int i = 0; i < 4; ++i)
#pragma unroll
    for (int j = 0; j < 4; ++j) acc[i][j] = (f32x4){0.f, 0.f, 0.f, 0.f};

  for (int k0 = 0; k0 < Kp; k0 += 32) {
    __syncthreads();
    GLOAD_LDS(ga0 + k0, &As[wave * 32][0]);
    GLOAD_LDS(ga1 + k0, &As[wave * 32 + 16][0]);
    GLOAD_LDS(gb0 + k0, &Bs[wave * 32][0]);
    GLOAD_LDS(gb1 + k0, &Bs[wave * 32 + 16][0]);
    __syncthreads();

    bf16x8 af[4], bfv[4];
#pragma unroll
    for (int i = 0; i < 4; ++i) af[i]  = *(const bf16x8*)&As[wm + i * 16 + l15][l4 * 8];
#pragma unroll
    for (int j = 0; j < 4; ++j) bfv[j] = *(const bf16x8*)&Bs[wn + j * 16 + l15][l4 * 8];
#pragma unroll
    for (int i = 0; i < 4; ++i)
#pragma unroll
      for (int j = 0; j < 4; ++j)
        acc[i][j] = __builtin_amdgcn_mfma_f32_16x16x32_bf16(af[i], bfv[j], acc[i][j], 0, 0, 0);
  }

#pragma unroll
  for (int j = 0; j < 4; ++j) {
    int gn = bn + wn + j * 16 + l15;
    float bsum = (bias1 ? bias1[gn] : 0.f) + (bias2 ? bias2[gn] : 0.f);
#pragma unroll
    for (int i = 0; i < 4; ++i) {
#pragma unroll
      for (int r = 0; r < 4; ++r) {
        int gm = bm + wm + i * 16 + l4 * 4 + r;
        C[(size_t)gm * N + gn] = acc[i][j][r] + bsum;
      }
    }
  }
}

// ---------------- Persistent BiLSTM scan (r12, proven) ----------------
__global__ __launch_bounds__(512, 2) void lstm_scan(
    const float* __restrict__ P,          // [8192][4096] x-proj + biases
    const float* __restrict__ whh,        // [2][2048][512]
    unsigned short* __restrict__ Hbf,     // [8192][1024] bf16 layer output
    unsigned int* __restrict__ hT,        // [2 parity][2 dir][32 b][256 u32]
    int* __restrict__ flags) {            // [2 dirs][32]
  int wg  = blockIdx.x;
  int dir = wg >> 5;
  int hb  = wg & 31;
  int tid = threadIdx.x;
  int wave = tid >> 6;
  int lane = tid & 63;
  int g  = wave & 3;
  int nb = wave >> 2;
  int l15 = lane & 15;
  int l4  = lane >> 4;

  // resident weight A-fragments (fp32 -> bf16), 64 VGPRs
  int grow = g * H_ + hb * 16 + l15;
  const float* wrow = whh + ((size_t)dir * G4_ + grow) * H_;
  bf16x8 afrag[16];
#pragma unroll
  for (int kk = 0; kk < 16; ++kk) {
    int k0 = kk * 32 + l4 * 8;
    float4 lo = *(const float4*)(wrow + k0);
    float4 hi = *(const float4*)(wrow + k0 + 4);
    bf16x8 a;
    a[0] = (short)f2bf(lo.x); a[1] = (short)f2bf(lo.y);
    a[2] = (short)f2bf(lo.z); a[3] = (short)f2bf(lo.w);
    a[4] = (short)f2bf(hi.x); a[5] = (short)f2bf(hi.y);
    a[6] = (short)f2bf(hi.z); a[7] = (short)f2bf(hi.w);
    afrag[kk] = a;
  }

  __shared__ float lds_g[4][16][32];
  __shared__ unsigned short hlds[32][520];   // 1040B row stride
  int* dflags = flags + dir * 32;

  // pointwise mapping: threads 0..255 handle 2 cells (hid pair) each
  bool pw = tid < 256;
  int pb = tid & 31, pq = (tid >> 5) & 7;  // batch, hid-pair index
  float c0 = 0.f, c1 = 0.f;
  float2 pfc[4], pfn[4];

  {
    int t0i = dir ? (S_ - 1) : 0;
    if (pw) {
      size_t pr = ((size_t)(t0i * B_ + pb)) * NG_ + (size_t)dir * G4_ + hb * 16 + 2 * pq;
#pragma unroll
      for (int gg = 0; gg < 4; ++gg) pfc[gg] = *(const float2*)(P + pr + gg * H_);
    }
  }

  // staging mapping: lane stages row (wave*4 + (lane&3)), 64B chunk (lane>>2)
  int srow   = wave * 4 + (lane & 3);
  int schunk = lane >> 2;
  const unsigned short* slabBase = (const unsigned short*)hT + (size_t)dir * (32 * 512);

  for (int s = 0; s < S_; ++s) {
    int t = dir ? (S_ - 1 - s) : s;

    f32x4 acc = {0.f, 0.f, 0.f, 0.f};
    if (s > 0) {
      const unsigned short* src = slabBase + (size_t)((s + 1) & 1) * (2 * 32 * 512)
                                  + srow * 512 + schunk * 32;
      bf16x8 t0, t1, t2, t3;
      asm volatile("global_load_dwordx4 %0, %1, off sc0 sc1"           : "=v"(t0) : "v"(src) : "memory");
      asm volatile("global_load_dwordx4 %0, %1, off offset:16 sc0 sc1" : "=v"(t1) : "v"(src) : "memory");
      asm volatile("global_load_dwordx4 %0, %1, off offset:32 sc0 sc1" : "=v"(t2) : "v"(src) : "memory");
      asm volatile("global_load_dwordx4 %0, %1, off offset:48 sc0 sc1" : "=v"(t3) : "v"(src) : "memory");
      if (pw && s < S_ - 1) {
        int tn = dir ? (S_ - 2 - s) : (s + 1);
        size_t pr = ((size_t)(tn * B_ + pb)) * NG_ + (size_t)dir * G4_ + hb * 16 + 2 * pq;
#pragma unroll
        for (int gg = 0; gg < 4; ++gg) pfn[gg] = *(const float2*)(P + pr + gg * H_);
        asm volatile("s_waitcnt vmcnt(4)" ::: "memory");
      } else {
        asm volatile("s_waitcnt vmcnt(0)" ::: "memory");
      }
      __builtin_amdgcn_sched_barrier(0);
      *(bf16x8*)&hlds[srow][schunk * 32 +  0] = t0;
      *(bf16x8*)&hlds[srow][schunk * 32 +  8] = t1;
      *(bf16x8*)&hlds[srow][schunk * 32 + 16] = t2;
      *(bf16x8*)&hlds[srow][schunk * 32 + 24] = t3;
      __syncthreads();   // stage visible to all waves

      bf16x8 bv[16];
#pragma unroll
      for (int kk = 0; kk < 16; ++kk)
        bv[kk] = *(const bf16x8*)&hlds[nb * 16 + l15][kk * 32 + l4 * 8];
#pragma unroll
      for (int kk = 0; kk < 16; ++kk)
        acc = __builtin_amdgcn_mfma_f32_16x16x32_bf16(afrag[kk], bv[kk], acc, 0, 0, 0);
    } else {
      if (pw) {   // prefetch for step 1
        int tn = dir ? (S_ - 2) : 1;
        size_t pr = ((size_t)(tn * B_ + pb)) * NG_ + (size_t)dir * G4_ + hb * 16 + 2 * pq;
#pragma unroll
        for (int gg = 0; gg < 4; ++gg) pfn[gg] = *(const float2*)(P + pr + gg * H_);
      }
    }

#pragma unroll
    for (int r = 0; r < 4; ++r)
      lds_g[g][l4 * 4 + r][l15 + 16 * nb] = acc[r];
    __syncthreads();

    if (pw) {
      int h0 = 2 * pq, h1 = 2 * pq + 1;
      float iv0 = lds_g[0][h0][pb] + pfc[0].x, iv1 = lds_g[0][h1][pb] + pfc[0].y;
      float fv0 = lds_g[1][h0][pb] + pfc[1].x, fv1 = lds_g[1][h1][pb] + pfc[1].y;
      float gv0 = lds_g[2][h0][pb] + pfc[2].x, gv1 = lds_g[2][h1][pb] + pfc[2].y;
      float ov0 = lds_g[3][h0][pb] + pfc[3].x, ov1 = lds_g[3][h1][pb] + pfc[3].y;
      float cn0 = sigm(fv0) * c0 + sigm(iv0) * tanhfast(gv0);
      float cn1 = sigm(fv1) * c1 + sigm(iv1) * tanhfast(gv1);
      float hn0 = sigm(ov0) * tanhfast(cn0);
      float hn1 = sigm(ov1) * tanhfast(cn1);
      c0 = cn0; c1 = cn1;
      unsigned int hp = (unsigned int)f2bf(hn0) | ((unsigned int)f2bf(hn1) << 16);
      *(unsigned int*)(Hbf + ((size_t)(t * B_ + pb)) * 1024 + dir * H_ + hb * 16 + 2 * pq) = hp;
      unsigned int* hc = hT + ((((size_t)(s & 1) * 2 + dir) * 32 + pb) * 256 + hb * 8 + pq);
      __hip_atomic_store(hc, hp, __ATOMIC_RELAXED, __HIP_MEMORY_SCOPE_AGENT);
#pragma unroll
      for (int gg = 0; gg < 4; ++gg) pfc[gg] = pfn[gg];
    }

    if (s < S_ - 1) {
      __syncthreads();   // drains vmcnt per wave: all hT stores at LLC
      if (wave == 0) {
        int target = s + 1;
        if (lane == 0)
          __hip_atomic_store(dflags + hb, target, __ATOMIC_RELAXED, __HIP_MEMORY_SCOPE_AGENT);
        int guard = 0;
        for (;;) {
          int v = target;
          if (lane < 32)
            v = __hip_atomic_load(dflags + lane, __ATOMIC_RELAXED, __HIP_MEMORY_SCOPE_AGENT);
          if (__all(v >= target)) break;
          __builtin_amdgcn_s_sleep(1);
          if (++guard > (1 << 17)) break;   // safety valve: wrong answer, not a hang
        }
      }
      __syncthreads();
    }
  }
}

// ---------------- fused highway + FC logits (one row per block) ----------------
// G12 = [8192][2048]: cols 0..1023 = T-gate pre-act (no bias), 1024..2047 = H pre-act.
__global__ __launch_bounds__(256) void hwfc_k(
    const unsigned int* __restrict__ Xbf,  // [8192][512] bf16 pairs (LSTM out)
    const float* __restrict__ G12,         // [8192][2048]
    const float* __restrict__ hw_Tb, const float* __restrict__ hw_Hb,
    const float* __restrict__ fc_w,        // [20][1024]
    const float* __restrict__ fc_b,        // [20]
    float* __restrict__ LOG) {             // [8192][20]
  int m = blockIdx.x;
  int tid = threadIdx.x;
  int wave = tid >> 6, lane = tid & 63;
  int e0 = tid * 4;

  unsigned int xv0 = Xbf[(size_t)m * 512 + tid * 2];
  unsigned int xv1 = Xbf[(size_t)m * 512 + tid * 2 + 1];
  float4 g1 = *(const float4*)(G12 + (size_t)m * 2048 + e0);
  float4 g2 = *(const float4*)(G12 + (size_t)m * 2048 + 1024 + e0);
  float4 tb = *(const float4*)(hw_Tb + e0);
  float4 hbv = *(const float4*)(hw_Hb + e0);
  g1.x += tb.x; g1.y += tb.y; g1.z += tb.z; g1.w += tb.w;
  g2.x += hbv.x; g2.y += hbv.y; g2.z += hbv.z; g2.w += hbv.w;
  float tg, o[4];
  tg = sigm(g1.x); o[0] = tg * fmaxf(g2.x, 0.f) + (1.f - tg) * bf2f(xv0 & 0xffffu);
  tg = sigm(g1.y); o[1] = tg * fmaxf(g2.y, 0.f) + (1.f - tg) * bf2f(xv0 >> 16);
  tg = sigm(g1.z); o[2] = tg * fmaxf(g2.z, 0.f) + (1.f - tg) * bf2f(xv1 & 0xffffu);
  tg = sigm(g1.w); o[3] = tg * fmaxf(g2.w, 0.f) + (1.f - tg) * bf2f(xv1 >> 16);

  float acc[T_];
#pragma unroll
  for (int j = 0; j < T_; ++j) {
    float4 w = *(const float4*)(fc_w + (size_t)j * 1024 + e0);
    acc[j] = o[0] * w.x + o[1] * w.y + o[2] * w.z + o[3] * w.w;
  }
#pragma unroll
  for (int off = 32; off > 0; off >>= 1)
#pragma unroll
    for (int j = 0; j < T_; ++j)
      acc[j] += __shfl_xor(acc[j], off);

  __shared__ float part[4][T_];
  if (lane == 0)
#pragma unroll
    for (int j = 0; j < T_; ++j) part[wave][j] = acc[j];
  __syncthreads();
  if (tid < T_)
    LOG[(size_t)m * T_ + tid] =
        part[0][tid] + part[1][tid] + part[2][tid] + part[3][tid] + fc_b[tid];
}

// ---------------- CRF gold score (parallel reduction over t) ----------------
__global__ __launch_bounds__(256) void crf_score_k(
    const int* __restrict__ x, const int* __restrict__ tags,
    const float* __restrict__ L,
    const float* __restrict__ cstart, const float* __restrict__ cend,
    const float* __restrict__ ctrans, float* __restrict__ score) {
  int b = blockIdx.x;
  int t = threadIdx.x;                   // S_ == 256 == blockDim
  int tg = tags[b * S_ + t];
  float part = 0.f;
  bool valid;
  if (t == 0) {
    part = cstart[tg] + L[(size_t)b * T_ + tg];
    valid = true;
  } else {
    valid = (x[b * S_ + t] != 0);
    if (valid)
      part = ctrans[tags[b * S_ + t - 1] * T_ + tg] + L[((size_t)t * B_ + b) * T_ + tg];
  }
  bool nextInvalid = (t == S_ - 1) || (x[b * S_ + t + 1] == 0);
  if (valid && nextInvalid) part += cend[tg];

  __shared__ float red[256];
  red[t] = part;
  __syncthreads();
  for (int off = 128; off > 0; off >>= 1) {
    if (t < off) red[t] += red[t + off];
    __syncthreads();
  }
  if (t == 0) score[b] = red[0];
}

// ---------------- CRF forward (log partition), one block per batch ----------------
__global__ __launch_bounds__(64) void crf_forward_k(
    const int* __restrict__ x, const float* __restrict__ L,
    const float* __restrict__ cstart, const float* __restrict__ cend,
    const float* __restrict__ ctrans, float* __restrict__ logz) {
  int b = blockIdx.x;
  int tp = threadIdx.x;
  __shared__ float alpha[T_];
  __shared__ float trT[T_][T_];
  for (int i = tp; i < T_ * T_; i += 64)
    trT[i / T_][i % T_] = ctrans[(i % T_) * T_ + (i / T_)];
  if (tp < T_) alpha[tp] = cstart[tp] + L[(size_t)b * T_ + tp];
  __syncthreads();
  for (int t = 1; t < S_; ++t) {
    float newv = 0.f;
    bool active = tp < T_;
    bool msk = x[b * S_ + t] != 0;
    if (active) {
      float em = L[((size_t)t * B_ + b) * T_ + tp];
      float mx = -1e30f;
#pragma unroll
      for (int tt = 0; tt < T_; ++tt) mx = fmaxf(mx, alpha[tt] + trT[tp][tt]);
      float sum = 0.f;
#pragma unroll
      for (int tt = 0; tt < T_; ++tt) sum += __expf(alpha[tt] + trT[tp][tt] - mx);
      float nxt = mx + __logf(sum) + em;
      newv = msk ? nxt : alpha[tp];
    }
    __syncthreads();
    if (active) alpha[tp] = newv;
    __syncthreads();
  }
  if (tp == 0) {
    float mx = -1e30f;
    for (int tt = 0; tt < T_; ++tt) mx = fmaxf(mx, alpha[tt] + cend[tt]);
    float sum = 0.f;
    for (int tt = 0; tt < T_; ++tt) sum += __expf(alpha[tt] + cend[tt] - mx);
    logz[b] = mx + __logf(sum);
  }
}

// ---------------- token NLL (aux loss) ----------------
__global__ __launch_bounds__(256) void nll_k(const float* __restrict__ L,
                                             const int* __restrict__ tags,
                                             float* __restrict__ accum) {
  int m = blockIdx.x * 256 + threadIdx.x;
  float nv = 0.f, vv = 0.f;
  if (m < B_ * S_) {
    int t = m >> 5, b = m & 31;
    int tg = tags[b * S_ + t];
    const float* row = L + (size_t)m * T_;
    float mx = -1e30f;
    for (int i = 0; i < T_; ++i) mx = fmaxf(mx, row[i]);
    float sum = 0.f;
    for (int i = 0; i < T_; ++i) sum += expf(row[i] - mx);
    float lse = mx + logf(sum);
    if (tg != 0) { nv = lse - row[tg]; vv = 1.f; }
  }
  __shared__ float sn[256], sv[256];
  int tid = threadIdx.x;
  sn[tid] = nv; sv[tid] = vv;
  __syncthreads();
  for (int off = 128; off > 0; off >>= 1) {
    if (tid < off) { sn[tid] += sn[tid + off]; sv[tid] += sv[tid + off]; }
    __syncthreads();
  }
  if (tid == 0) { atomicAdd(&accum[0], sn[0]); atomicAdd(&accum[1], sv[0]); }
}

// ---------------- final scalar ----------------
__global__ void final_k(const float* __restrict__ score, const float* __restrict__ logz,
                        const float* __restrict__ accum, float* __restrict__ out) {
  if (threadIdx.x == 0 && blockIdx.x == 0) {
    float s = 0.f;
    for (int b = 0; b < B_; ++b) s += score[b] - logz[b];
    float crf = -s / (float)B_;
    out[0] = crf + 0.1f * (accum[0] / accum[1]);
  }
}

extern "C" void kernel_launch(void* const* d_in, const int* in_sizes, int n_in,
                              void* d_out, int out_size, void* d_ws, size_t ws_size,
                              hipStream_t stream) {
  (void)in_sizes; (void)n_in; (void)out_size; (void)ws_size;
  const int*   x      = (const int*)d_in[0];
  const int*   xc     = (const int*)d_in[1];
  const int*   tags   = (const int*)d_in[2];
  const float* wemb   = (const float*)d_in[3];
  const float* cemb   = (const float*)d_in[4];
  const float* w2     = (const float*)d_in[5];
  const float* cb2    = (const float*)d_in[6];
  const float* w3     = (const float*)d_in[7];
  const float* cb3    = (const float*)d_in[8];
  const float* w4     = (const float*)d_in[9];
  const float* cb4    = (const float*)d_in[10];
  const float* l0_wih = (const float*)d_in[11];
  const float* l0_whh = (const float*)d_in[12];
  const float* l0_bih = (const float*)d_in[13];
  const float* l0_bhh = (const float*)d_in[14];
  const float* l1_wih = (const float*)d_in[15];
  const float* l1_whh = (const float*)d_in[16];
  const float* l1_bih = (const float*)d_in[17];
  const float* l1_bhh = (const float*)d_in[18];
  const float* hw_Hw  = (const float*)d_in[19];
  const float* hw_Hb  = (const float*)d_in[20];
  const float* hw_Tw  = (const float*)d_in[21];
  const float* hw_Tb  = (const float*)d_in[22];
  const float* fc_w   = (const float*)d_in[23];
  const float* fc_b   = (const float*)d_in[24];
  const float* cstart = (const float*)d_in[25];
  const float* cend   = (const float*)d_in[26];
  const float* ctrans = (const float*)d_in[27];

  // workspace layout (float units), total ~42.01M floats ~= 168 MB
  float* ws    = (float*)d_ws;
  float* P     = ws;                              // [0, 33554432)
  float* G12   = P;                               // alias (P dead after scans): 8192*2048
  unsigned short* Hbf    = (unsigned short*)(ws + 33554432);   // 8192*1024 bf16
  unsigned short* COMBbf = (unsigned short*)(ws + 37748736);   // 8192*480 bf16
  unsigned short* Wbf    = (unsigned short*)(ws + 39714816);   // 4096*1024 bf16
  float* LOG   = ws + 41811968;                   // 163,840
  unsigned int* hT = (unsigned int*)(ws + 41975808);  // 32,768 u32
  int*   flags = (int*)(ws + 42008576);           // 128 ints
  float* score = ws + 42008576 + 128;
  float* logz  = score + 32;
  float* accum = logz + 32;

  hipMemsetAsync(accum, 0, 2 * sizeof(float), stream);

  // 1. embedding + char CNN -> bf16 padded
  embed_cnn<<<B_ * S_, 256, 0, stream>>>(x, xc, wemb, cemb, w2, cb2, w3, cb3, w4, cb4, COMBbf);

  // 2. layer0 input projection (bf16 MFMA)
  castpad<<<(4096 * KP0_ + 255) / 256, 256, 0, stream>>>(l0_wih, Wbf, 4096, IN0_, KP0_);
  {
    dim3 g(NG_ / 128, (B_ * S_) / 128);
    gemm_bf16<<<g, 256, 0, stream>>>(COMBbf, Wbf, l0_bih, l0_bhh, P, B_ * S_, NG_, KP0_);
  }
  // 3. layer0 recurrence
  hipMemsetAsync(flags, 0, 128 * sizeof(int), stream);
  lstm_scan<<<64, 512, 0, stream>>>(P, l0_whh, Hbf, hT, flags);

  // 4. layer1 input projection
  castpad<<<(4096 * 1024 + 255) / 256, 256, 0, stream>>>(l1_wih, Wbf, 4096, 1024, 1024);
  {
    dim3 g(NG_ / 128, (B_ * S_) / 128);
    gemm_bf16<<<g, 256, 0, stream>>>(Hbf, Wbf, l1_bih, l1_bhh, P, B_ * S_, NG_, 1024);
  }
  // 5. layer1 recurrence
  hipMemsetAsync(flags, 0, 128 * sizeof(int), stream);
  lstm_scan<<<64, 512, 0, stream>>>(P, l1_whh, Hbf, hT, flags);

  // 6. fused highway gate GEMM: W = [hw_Tw ; hw_Hw] (2048 x 1024), one pass over A
  castpad<<<(1024 * 1024 + 255) / 256, 256, 0, stream>>>(hw_Tw, Wbf, 1024, 1024, 1024);
  castpad<<<(1024 * 1024 + 255) / 256, 256, 0, stream>>>(hw_Hw, Wbf + 1024 * 1024, 1024, 1024, 1024);
  {
    dim3 g(2048 / 128, (B_ * S_) / 128);
    gemm_bf16<<<g, 256, 0, stream>>>(Hbf, Wbf, nullptr, nullptr, G12, B_ * S_, 2048, 1024);
  }
  // 7. fused highway combine + fc logits (biases applied here)
  hwfc_k<<<B_ * S_, 256, 0, stream>>>(
      (const unsigned int*)Hbf, G12, hw_Tb, hw_Hb, fc_w, fc_b, LOG);

  // 8. CRF + losses
  crf_score_k<<<B_, 256, 0, stream>>>(x, tags, LOG, cstart, cend, ctrans, score);
  crf_forward_k<<<B_, 64, 0, stream>>>(x, LOG, cstart, cend, ctrans, logz);
  nll_k<<<(B_ * S_ + 255) / 256, 256, 0, stream>>>(LOG, tags, accum);
  final_k<<<1, 64, 0, stream>>>(score, logz, accum, (float*)d_out);
}

// Round 17
// 3288.847 us; speedup vs baseline: 1.1995x; 1.0325x over previous
//
#include <hip/hip_runtime.h>
#include <math.h>

// Model dims
#define B_   32
#define S_   256
#define T_   20
#define H_   512
#define E_   300
#define C_   16
#define CE_  30
#define NF_  50
#define IN0_ 450      // E + 3*NF
#define KP0_ 480      // IN0 padded to %32
#define G4_  2048     // 4*H
#define NG_  4096     // 2 dirs * 4H

typedef __attribute__((ext_vector_type(8))) short bf16x8;
typedef __attribute__((ext_vector_type(4))) float f32x4;

__device__ __forceinline__ float sigm(float x) { return 1.f / (1.f + __expf(-x)); }
__device__ __forceinline__ float tanhfast(float x) {
  x = fminf(15.f, fmaxf(-15.f, x));
  float e = __expf(-2.f * x);
  return (1.f - e) / (1.f + e);
}
__device__ __forceinline__ unsigned short f2bf(float f) {
  unsigned int u = __float_as_uint(f);
  unsigned int r = (u + 0x7fffu + ((u >> 16) & 1u)) >> 16;
  return (unsigned short)r;
}
__device__ __forceinline__ float bf2f(unsigned int u) {
  return __uint_as_float(u << 16);
}

// direct global->LDS staging (16B/lane, wave-uniform LDS base + lane*16)
#define GLOAD_LDS(gp, lp)                                                    \
  __builtin_amdgcn_global_load_lds(                                          \
      (const __attribute__((address_space(1))) void*)(gp),                   \
      (__attribute__((address_space(3))) void*)(lp), 16, 0, 0)

// ---------------- Embedding + char CNN -> bf16 padded [8192][480] ----------------
__global__ __launch_bounds__(256) void embed_cnn(
    const int* __restrict__ x, const int* __restrict__ xc,
    const float* __restrict__ wemb, const float* __restrict__ cemb,
    const float* __restrict__ w2, const float* __restrict__ cb2,
    const float* __restrict__ w3, const float* __restrict__ cb3,
    const float* __restrict__ w4, const float* __restrict__ cb4,
    unsigned short* __restrict__ out) {
  int m = blockIdx.x;           // m = t*32 + b
  int t = m >> 5, b = m & 31;
  int tid = threadIdx.x;
  __shared__ float emb[C_][CE_];
  __shared__ float conv[2100];

  int wid = x[b * S_ + t];
  for (int e = tid; e < KP0_; e += 256) {
    if (e < E_) out[(size_t)m * KP0_ + e] = f2bf(wemb[(size_t)wid * E_ + e]);
    else if (e >= IN0_) out[(size_t)m * KP0_ + e] = 0;
  }

  for (int idx = tid; idx < C_ * CE_; idx += 256) {
    int c = idx / CE_, ce = idx % CE_;
    int cid = xc[(b * S_ + t) * C_ + c];
    emb[c][ce] = cemb[cid * CE_ + ce];
  }
  __syncthreads();

  for (int idx = tid; idx < 2100; idx += 256) {
    int kw, f, p;
    const float* w; const float* bb;
    int r = idx;
    if (r < 750)      { kw = 2; f = r / 15; p = r % 15; w = w2; bb = cb2; }
    else if (r < 1450){ r -= 750;  kw = 3; f = r / 14; p = r % 14; w = w3; bb = cb3; }
    else              { r -= 1450; kw = 4; f = r / 13; p = r % 13; w = w4; bb = cb4; }
    float acc = bb[f];
    for (int j = 0; j < kw; ++j)
      for (int ce = 0; ce < CE_; ++ce)
        acc = fmaf(emb[p + j][ce], w[(f * CE_ + ce) * kw + j], acc);
    conv[idx] = fmaxf(acc, 0.f);
  }
  __syncthreads();

  if (tid < 150) {
    int kk = tid / 50, f = tid % 50;
    int base, np;
    if (kk == 0)      { base = f * 15;        np = 15; }
    else if (kk == 1) { base = 750 + f * 14;  np = 14; }
    else              { base = 1450 + f * 13; np = 13; }
    float mx = 0.f;
    for (int p = 0; p < np; ++p) mx = fmaxf(mx, conv[base + p]);
    out[(size_t)m * KP0_ + E_ + kk * 50 + f] = f2bf(mx);
  }
}

// ---------------- fp32 -> bf16 cast with K padding ----------------
__global__ __launch_bounds__(256) void castpad(
    const float* __restrict__ src, unsigned short* __restrict__ dst,
    int R, int K, int Kp) {
  int i = blockIdx.x * 256 + threadIdx.x;
  if (i < R * Kp) {
    int r = i / Kp, k = i - r * Kp;
    dst[i] = (k < K) ? f2bf(src[(size_t)r * K + k]) : (unsigned short)0;
  }
}

// ---------------- bf16 MFMA GEMM (global_load_lds staging): C = A @ W^T + b1 + b2 ----------------
__global__ __launch_bounds__(256) void gemm_bf16(
    const unsigned short* __restrict__ A, const unsigned short* __restrict__ W,
    const float* __restrict__ bias1, const float* __restrict__ bias2,
    float* __restrict__ C, int M, int N, int Kp) {
  __shared__ unsigned short As[128][32];   // linear: row = 64B (required by gload_lds)
  __shared__ unsigned short Bs[128][32];
  int bm = blockIdx.y * 128, bn = blockIdx.x * 128;
  int tid = threadIdx.x;
  int wave = tid >> 6, lane = tid & 63;
  int wm = (wave & 1) * 64, wn = (wave >> 1) * 64;
  int l15 = lane & 15, l4 = lane >> 4;

  int srow = lane >> 2;
  int scol = (lane & 3) * 8;
  const unsigned short* ga0 = A + (size_t)(bm + wave * 32 + srow) * Kp + scol;
  const unsigned short* ga1 = A + (size_t)(bm + wave * 32 + 16 + srow) * Kp + scol;
  const unsigned short* gb0 = W + (size_t)(bn + wave * 32 + srow) * Kp + scol;
  const unsigned short* gb1 = W + (size_t)(bn + wave * 32 + 16 + srow) * Kp + scol;

  f32x4 acc[4][4];
#pragma unroll
  for (int i = 0; i < 4; ++i)
#pragma unroll
    for (int j = 0; j < 4; ++j) acc[i][j] = (f32x4){0.f, 0.f, 0.f, 0.f};

  for (int k0 = 0; k0 < Kp; k0 += 32) {
    __syncthreads();
    GLOAD_LDS(ga0 + k0, &As[wave * 32][0]);
    GLOAD_LDS(ga1 + k0, &As[wave * 32 + 16][0]);
    GLOAD_LDS(gb0 + k0, &Bs[wave * 32][0]);
    GLOAD_LDS(gb1 + k0, &Bs[wave * 32 + 16][0]);
    __syncthreads();

    bf16x8 af[4], bfv[4];
#pragma unroll
    for (int i = 0; i < 4; ++i) af[i]  = *(const bf16x8*)&As[wm + i * 16 + l15][l4 * 8];
#pragma unroll
    for (int j = 0; j < 4; ++j) bfv[j] = *(const bf16x8*)&Bs[wn + j * 16 + l15][l4 * 8];
#pragma unroll
    for (int i = 0; i < 4; ++i)
#pragma unroll
      for (int j = 0; j < 4; ++j)
        acc[i][j] = __builtin_amdgcn_mfma_f32_16x16x32_bf16(af[i], bfv[j], acc[i][j], 0, 0, 0);
  }

#pragma unroll
  for (int j = 0; j < 4; ++j) {
    int gn = bn + wn + j * 16 + l15;
    float bsum = (bias1 ? bias1[gn] : 0.f) + (bias2 ? bias2[gn] : 0.f);
#pragma unroll
    for (int i = 0; i < 4; ++i) {
#pragma unroll
      for (int r = 0; r < 4; ++r) {
        int gm = bm + wm + i * 16 + l4 * 4 + r;
        C[(size_t)gm * N + gn] = acc[i][j][r] + bsum;
      }
    }
  }
}

// ---------------- Persistent BiLSTM scan: r12 shell + fused gates-in-lane ----------------
// 64 WGs: dir = wg>>5, hb = wg&31 (16 hidden units). 512 threads = 8 waves:
// wave = (hq 0..3) x (nb 0..1): hidden quad hq, batch half nb. Wave's 16 MFMA
// A-rows reordered as (hh = l15>>2, gate = l15&3), so C-layout (col=batch l15,
// row=(l4)*4+reg) puts ALL 4 GATES of cell (hb*16+hq*4+l4, nb*16+l15) in one
// lane's acc[0..3]. Pointwise fuses on the accumulator: no lds_g, no gate
// barrier, pointwise parallel on all 8 waves. Pair packing via shfl_xor(.,16)
// (verified absmax-0 in the r15 variant). Staging/protocol identical to r12.
__global__ __launch_bounds__(512, 2) void lstm_scan(
    const float* __restrict__ P,          // [8192][4096] x-proj + biases
    const float* __restrict__ whh,        // [2][2048][512]
    unsigned int* __restrict__ Hbf32,     // [8192][512] u32 = bf16 pairs
    unsigned int* __restrict__ hT,        // [2 parity][2 dir][32 b][256 u32]
    int* __restrict__ flags) {            // [2 dirs][32]
  int wg  = blockIdx.x;
  int dir = wg >> 5;
  int hb  = wg & 31;
  int tid = threadIdx.x;
  int wave = tid >> 6;
  int lane = tid & 63;
  int hq = wave >> 1;
  int nb = wave & 1;
  int l15 = lane & 15;
  int l4  = lane >> 4;
  int hidx = hb * 16 + hq * 4 + l4;       // this lane's hidden unit
  int bidx = nb * 16 + l15;               // this lane's batch element

  // resident weight A-fragments: A-row l15 <-> (hh = l15>>2, gate = l15&3)
  {
  }
  int arow_h = hb * 16 + hq * 4 + (l15 >> 2);
  int arow_g = l15 & 3;
  const float* wrow = whh + ((size_t)dir * G4_ + arow_g * H_ + arow_h) * H_;
  bf16x8 afrag[16];
#pragma unroll
  for (int kk = 0; kk < 16; ++kk) {
    int k0 = kk * 32 + l4 * 8;
    float4 lo = *(const float4*)(wrow + k0);
    float4 hi = *(const float4*)(wrow + k0 + 4);
    bf16x8 a;
    a[0] = (short)f2bf(lo.x); a[1] = (short)f2bf(lo.y);
    a[2] = (short)f2bf(lo.z); a[3] = (short)f2bf(lo.w);
    a[4] = (short)f2bf(hi.x); a[5] = (short)f2bf(hi.y);
    a[6] = (short)f2bf(hi.z); a[7] = (short)f2bf(hi.w);
    afrag[kk] = a;
  }

  __shared__ unsigned short hlds[32][520];   // 1040B row stride
  int* dflags = flags + dir * 32;

  float cst = 0.f;                           // cell state for (hidx, bidx)
  float pfc[4], pfn[4];                      // P per gate (i,f,g,o)

  {
    int t0i = dir ? (S_ - 1) : 0;
    size_t pr = ((size_t)(t0i * B_ + bidx)) * NG_ + (size_t)dir * G4_ + hidx;
#pragma unroll
    for (int gg = 0; gg < 4; ++gg) pfc[gg] = P[pr + gg * H_];
  }

  // staging mapping: lane stages row (wave*4 + (lane&3)), 64B chunk (lane>>2)
  int srow   = wave * 4 + (lane & 3);
  int schunk = lane >> 2;
  const unsigned short* slabBase = (const unsigned short*)hT + (size_t)dir * (32 * 512);

  for (int s = 0; s < S_; ++s) {
    int t = dir ? (S_ - 1 - s) : s;

    f32x4 acc = {0.f, 0.f, 0.f, 0.f};
    if (s > 0) {
      const unsigned short* src = slabBase + (size_t)((s + 1) & 1) * (2 * 32 * 512)
                                  + srow * 512 + schunk * 32;
      bf16x8 t0, t1, t2, t3;
      asm volatile("global_load_dwordx4 %0, %1, off sc0 sc1"           : "=v"(t0) : "v"(src) : "memory");
      asm volatile("global_load_dwordx4 %0, %1, off offset:16 sc0 sc1" : "=v"(t1) : "v"(src) : "memory");
      asm volatile("global_load_dwordx4 %0, %1, off offset:32 sc0 sc1" : "=v"(t2) : "v"(src) : "memory");
      asm volatile("global_load_dwordx4 %0, %1, off offset:48 sc0 sc1" : "=v"(t3) : "v"(src) : "memory");
      // prefetch next step's P while stage loads are in flight; wait for the
      // STAGE loads only (4 younger P loads stay outstanding).
      if (s < S_ - 1) {
        int tn = dir ? (S_ - 2 - s) : (s + 1);
        size_t pr = ((size_t)(tn * B_ + bidx)) * NG_ + (size_t)dir * G4_ + hidx;
#pragma unroll
        for (int gg = 0; gg < 4; ++gg) pfn[gg] = P[pr + gg * H_];
        asm volatile("s_waitcnt vmcnt(4)" ::: "memory");
      } else {
        asm volatile("s_waitcnt vmcnt(0)" ::: "memory");
      }
      __builtin_amdgcn_sched_barrier(0);
      *(bf16x8*)&hlds[srow][schunk * 32 +  0] = t0;
      *(bf16x8*)&hlds[srow][schunk * 32 +  8] = t1;
      *(bf16x8*)&hlds[srow][schunk * 32 + 16] = t2;
      *(bf16x8*)&hlds[srow][schunk * 32 + 24] = t3;
      __syncthreads();   // stage visible to all waves

      bf16x8 bv[16];
#pragma unroll
      for (int kk = 0; kk < 16; ++kk)
        bv[kk] = *(const bf16x8*)&hlds[nb * 16 + l15][kk * 32 + l4 * 8];
#pragma unroll
      for (int kk = 0; kk < 16; ++kk)
        acc = __builtin_amdgcn_mfma_f32_16x16x32_bf16(afrag[kk], bv[kk], acc, 0, 0, 0);
    } else {
      // prefetch for step 1
      int tn = dir ? (S_ - 2) : 1;
      size_t pr = ((size_t)(tn * B_ + bidx)) * NG_ + (size_t)dir * G4_ + hidx;
#pragma unroll
      for (int gg = 0; gg < 4; ++gg) pfn[gg] = P[pr + gg * H_];
    }

    // pointwise, in-lane (all 8 waves): acc reg r = gate r (i,f,g,o)
    {
      float iv = acc[0] + pfc[0];
      float fv = acc[1] + pfc[1];
      float gv = acc[2] + pfc[2];
      float ov = acc[3] + pfc[3];
      cst = sigm(fv) * cst + sigm(iv) * tanhfast(gv);
      float hn = sigm(ov) * tanhfast(cst);
      // pack hidden pair (hidx even lane | hidx^1 from lane^16) into u32
      unsigned int m = (unsigned int)f2bf(hn);
      unsigned int pm = (unsigned int)__shfl_xor((int)m, 16);
      if ((l4 & 1) == 0) {
        unsigned int w = m | (pm << 16);
        int hw = hidx >> 1;                  // hb*8 + hq*2 + l4/2
        Hbf32[((size_t)(t * B_ + bidx)) * 512 + dir * 256 + hw] = w;
        unsigned int* hc = hT + (((size_t)(s & 1) * 2 + dir) * 32 + bidx) * 256 + hw;
        __hip_atomic_store(hc, w, __ATOMIC_RELAXED, __HIP_MEMORY_SCOPE_AGENT);
      }
      // rotate P double-buffer
#pragma unroll
      for (int gg = 0; gg < 4; ++gg) pfc[gg] = pfn[gg];
    }

    if (s < S_ - 1) {
      __syncthreads();   // drains vmcnt per wave: all hT stores at LLC
      if (wave == 0) {
        int target = s + 1;
        if (lane == 0)
          __hip_atomic_store(dflags + hb, target, __ATOMIC_RELAXED, __HIP_MEMORY_SCOPE_AGENT);
        int guard = 0;
        for (;;) {
          int v = target;
          if (lane < 32)
            v = __hip_atomic_load(dflags + lane, __ATOMIC_RELAXED, __HIP_MEMORY_SCOPE_AGENT);
          if (__all(v >= target)) break;
          __builtin_amdgcn_s_sleep(1);
          if (++guard > (1 << 17)) break;   // safety valve: wrong answer, not a hang
        }
      }
      __syncthreads();
    }
  }
}

// ---------------- fused highway + FC logits (one row per block) ----------------
// G12 = [8192][2048]: cols 0..1023 = T-gate pre-act (no bias), 1024..2047 = H pre-act.
__global__ __launch_bounds__(256) void hwfc_k(
    const unsigned int* __restrict__ Xbf,  // [8192][512] bf16 pairs (LSTM out)
    const float* __restrict__ G12,         // [8192][2048]
    const float* __restrict__ hw_Tb, const float* __restrict__ hw_Hb,
    const float* __restrict__ fc_w,        // [20][1024]
    const float* __restrict__ fc_b,        // [20]
    float* __restrict__ LOG) {             // [8192][20]
  int m = blockIdx.x;
  int tid = threadIdx.x;
  int wave = tid >> 6, lane = tid & 63;
  int e0 = tid * 4;

  unsigned int xv0 = Xbf[(size_t)m * 512 + tid * 2];
  unsigned int xv1 = Xbf[(size_t)m * 512 + tid * 2 + 1];
  float4 g1 = *(const float4*)(G12 + (size_t)m * 2048 + e0);
  float4 g2 = *(const float4*)(G12 + (size_t)m * 2048 + 1024 + e0);
  float4 tb = *(const float4*)(hw_Tb + e0);
  float4 hbv = *(const float4*)(hw_Hb + e0);
  g1.x += tb.x; g1.y += tb.y; g1.z += tb.z; g1.w += tb.w;
  g2.x += hbv.x; g2.y += hbv.y; g2.z += hbv.z; g2.w += hbv.w;
  float tg, o[4];
  tg = sigm(g1.x); o[0] = tg * fmaxf(g2.x, 0.f) + (1.f - tg) * bf2f(xv0 & 0xffffu);
  tg = sigm(g1.y); o[1] = tg * fmaxf(g2.y, 0.f) + (1.f - tg) * bf2f(xv0 >> 16);
  tg = sigm(g1.z); o[2] = tg * fmaxf(g2.z, 0.f) + (1.f - tg) * bf2f(xv1 & 0xffffu);
  tg = sigm(g1.w); o[3] = tg * fmaxf(g2.w, 0.f) + (1.f - tg) * bf2f(xv1 >> 16);

  float acc[T_];
#pragma unroll
  for (int j = 0; j < T_; ++j) {
    float4 w = *(const float4*)(fc_w + (size_t)j * 1024 + e0);
    acc[j] = o[0] * w.x + o[1] * w.y + o[2] * w.z + o[3] * w.w;
  }
#pragma unroll
  for (int off = 32; off > 0; off >>= 1)
#pragma unroll
    for (int j = 0; j < T_; ++j)
      acc[j] += __shfl_xor(acc[j], off);

  __shared__ float part[4][T_];
  if (lane == 0)
#pragma unroll
    for (int j = 0; j < T_; ++j) part[wave][j] = acc[j];
  __syncthreads();
  if (tid < T_)
    LOG[(size_t)m * T_ + tid] =
        part[0][tid] + part[1][tid] + part[2][tid] + part[3][tid] + fc_b[tid];
}

// ---------------- CRF gold score (parallel reduction over t) ----------------
__global__ __launch_bounds__(256) void crf_score_k(
    const int* __restrict__ x, const int* __restrict__ tags,
    const float* __restrict__ L,
    const float* __restrict__ cstart, const float* __restrict__ cend,
    const float* __restrict__ ctrans, float* __restrict__ score) {
  int b = blockIdx.x;
  int t = threadIdx.x;                   // S_ == 256 == blockDim
  int tg = tags[b * S_ + t];
  float part = 0.f;
  bool valid;
  if (t == 0) {
    part = cstart[tg] + L[(size_t)b * T_ + tg];
    valid = true;
  } else {
    valid = (x[b * S_ + t] != 0);
    if (valid)
      part = ctrans[tags[b * S_ + t - 1] * T_ + tg] + L[((size_t)t * B_ + b) * T_ + tg];
  }
  bool nextInvalid = (t == S_ - 1) || (x[b * S_ + t + 1] == 0);
  if (valid && nextInvalid) part += cend[tg];

  __shared__ float red[256];
  red[t] = part;
  __syncthreads();
  for (int off = 128; off > 0; off >>= 1) {
    if (t < off) red[t] += red[t + off];
    __syncthreads();
  }
  if (t == 0) score[b] = red[0];
}

// ---------------- CRF forward (log partition), one block per batch ----------------
__global__ __launch_bounds__(64) void crf_forward_k(
    const int* __restrict__ x, const float* __restrict__ L,
    const float* __restrict__ cstart, const float* __restrict__ cend,
    const float* __restrict__ ctrans, float* __restrict__ logz) {
  int b = blockIdx.x;
  int tp = threadIdx.x;
  __shared__ float alpha[T_];
  __shared__ float trT[T_][T_];
  for (int i = tp; i < T_ * T_; i += 64)
    trT[i / T_][i % T_] = ctrans[(i % T_) * T_ + (i / T_)];
  if (tp < T_) alpha[tp] = cstart[tp] + L[(size_t)b * T_ + tp];
  __syncthreads();
  for (int t = 1; t < S_; ++t) {
    float newv = 0.f;
    bool active = tp < T_;
    bool msk = x[b * S_ + t] != 0;
    if (active) {
      float em = L[((size_t)t * B_ + b) * T_ + tp];
      float mx = -1e30f;
#pragma unroll
      for (int tt = 0; tt < T_; ++tt) mx = fmaxf(mx, alpha[tt] + trT[tp][tt]);
      float sum = 0.f;
#pragma unroll
      for (int tt = 0; tt < T_; ++tt) sum += __expf(alpha[tt] + trT[tp][tt] - mx);
      float nxt = mx + __logf(sum) + em;
      newv = msk ? nxt : alpha[tp];
    }
    __syncthreads();
    if (active) alpha[tp] = newv;
    __syncthreads();
  }
  if (tp == 0) {
    float mx = -1e30f;
    for (int tt = 0; tt < T_; ++tt) mx = fmaxf(mx, alpha[tt] + cend[tt]);
    float sum = 0.f;
    for (int tt = 0; tt < T_; ++tt) sum += __expf(alpha[tt] + cend[tt] - mx);
    logz[b] = mx + __logf(sum);
  }
}

// ---------------- token NLL (aux loss) ----------------
__global__ __launch_bounds__(256) void nll_k(const float* __restrict__ L,
                                             const int* __restrict__ tags,
                                             float* __restrict__ accum) {
  int m = blockIdx.x * 256 + threadIdx.x;
  float nv = 0.f, vv = 0.f;
  if (m < B_ * S_) {
    int t = m >> 5, b = m & 31;
    int tg = tags[b * S_ + t];
    const float* row = L + (size_t)m * T_;
    float mx = -1e30f;
    for (int i = 0; i < T_; ++i) mx = fmaxf(mx, row[i]);
    float sum = 0.f;
    for (int i = 0; i < T_; ++i) sum += expf(row[i] - mx);
    float lse = mx + logf(sum);
    if (tg != 0) { nv = lse - row[tg]; vv = 1.f; }
  }
  __shared__ float sn[256], sv[256];
  int tid = threadIdx.x;
  sn[tid] = nv; sv[tid] = vv;
  __syncthreads();
  for (int off = 128; off > 0; off >>= 1) {
    if (tid < off) { sn[tid] += sn[tid + off]; sv[tid] += sv[tid + off]; }
    __syncthreads();
  }
  if (tid == 0) { atomicAdd(&accum[0], sn[0]); atomicAdd(&accum[1], sv[0]); }
}

// ---------------- final scalar ----------------
__global__ void final_k(const float* __restrict__ score, const float* __restrict__ logz,
                        const float* __restrict__ accum, float* __restrict__ out) {
  if (threadIdx.x == 0 && blockIdx.x == 0) {
    float s = 0.f;
    for (int b = 0; b < B_; ++b) s += score[b] - logz[b];
    float crf = -s / (float)B_;
    out[0] = crf + 0.1f * (accum[0] / accum[1]);
  }
}

extern "C" void kernel_launch(void* const* d_in, const int* in_sizes, int n_in,
                              void* d_out, int out_size, void* d_ws, size_t ws_size,
                              hipStream_t stream) {
  (void)in_sizes; (void)n_in; (void)out_size; (void)ws_size;
  const int*   x      = (const int*)d_in[0];
  const int*   xc     = (const int*)d_in[1];
  const int*   tags   = (const int*)d_in[2];
  const float* wemb   = (const float*)d_in[3];
  const float* cemb   = (const float*)d_in[4];
  const float* w2     = (const float*)d_in[5];
  const float* cb2    = (const float*)d_in[6];
  const float* w3     = (const float*)d_in[7];
  const float* cb3    = (const float*)d_in[8];
  const float* w4     = (const float*)d_in[9];
  const float* cb4    = (const float*)d_in[10];
  const float* l0_wih = (const float*)d_in[11];
  const float* l0_whh = (const float*)d_in[12];
  const float* l0_bih = (const float*)d_in[13];
  const float* l0_bhh = (const float*)d_in[14];
  const float* l1_wih = (const float*)d_in[15];
  const float* l1_whh = (const float*)d_in[16];
  const float* l1_bih = (const float*)d_in[17];
  const float* l1_bhh = (const float*)d_in[18];
  const float* hw_Hw  = (const float*)d_in[19];
  const float* hw_Hb  = (const float*)d_in[20];
  const float* hw_Tw  = (const float*)d_in[21];
  const float* hw_Tb  = (const float*)d_in[22];
  const float* fc_w   = (const float*)d_in[23];
  const float* fc_b   = (const float*)d_in[24];
  const float* cstart = (const float*)d_in[25];
  const float* cend   = (const float*)d_in[26];
  const float* ctrans = (const float*)d_in[27];

  // workspace layout (float units), total ~42.01M floats ~= 168 MB
  float* ws    = (float*)d_ws;
  float* P     = ws;                              // [0, 33554432)
  float* G12   = P;                               // alias (P dead after scans): 8192*2048
  unsigned short* Hbf    = (unsigned short*)(ws + 33554432);   // 8192*1024 bf16
  unsigned short* COMBbf = (unsigned short*)(ws + 37748736);   // 8192*480 bf16
  unsigned short* Wbf    = (unsigned short*)(ws + 39714816);   // 4096*1024 bf16
  float* LOG   = ws + 41811968;                   // 163,840
  unsigned int* hT = (unsigned int*)(ws + 41975808);  // 32,768 u32
  int*   flags = (int*)(ws + 42008576);           // 128 ints
  float* score = ws + 42008576 + 128;
  float* logz  = score + 32;
  float* accum = logz + 32;

  hipMemsetAsync(accum, 0, 2 * sizeof(float), stream);

  // 1. embedding + char CNN -> bf16 padded
  embed_cnn<<<B_ * S_, 256, 0, stream>>>(x, xc, wemb, cemb, w2, cb2, w3, cb3, w4, cb4, COMBbf);

  // 2. layer0 input projection (bf16 MFMA)
  castpad<<<(4096 * KP0_ + 255) / 256, 256, 0, stream>>>(l0_wih, Wbf, 4096, IN0_, KP0_);
  {
    dim3 g(NG_ / 128, (B_ * S_) / 128);
    gemm_bf16<<<g, 256, 0, stream>>>(COMBbf, Wbf, l0_bih, l0_bhh, P, B_ * S_, NG_, KP0_);
  }
  // 3. layer0 recurrence
  hipMemsetAsync(flags, 0, 128 * sizeof(int), stream);
  lstm_scan<<<64, 512, 0, stream>>>(P, l0_whh, (unsigned int*)Hbf, hT, flags);

  // 4. layer1 input projection
  castpad<<<(4096 * 1024 + 255) / 256, 256, 0, stream>>>(l1_wih, Wbf, 4096, 1024, 1024);
  {
    dim3 g(NG_ / 128, (B_ * S_) / 128);
    gemm_bf16<<<g, 256, 0, stream>>>(Hbf, Wbf, l1_bih, l1_bhh, P, B_ * S_, NG_, 1024);
  }
  // 5. layer1 recurrence
  hipMemsetAsync(flags, 0, 128 * sizeof(int), stream);
  lstm_scan<<<64, 512, 0, stream>>>(P, l1_whh, (unsigned int*)Hbf, hT, flags);

  // 6. fused highway gate GEMM: W = [hw_Tw ; hw_Hw] (2048 x 1024), one pass over A
  castpad<<<(1024 * 1024 + 255) / 256, 256, 0, stream>>>(hw_Tw, Wbf, 1024, 1024, 1024);
  castpad<<<(1024 * 1024 + 255) / 256, 256, 0, stream>>>(hw_Hw, Wbf + 1024 * 1024, 1024, 1024, 1024);
  {
    dim3 g(2048 / 128, (B_ * S_) / 128);
    gemm_bf16<<<g, 256, 0, stream>>>(Hbf, Wbf, nullptr, nullptr, G12, B_ * S_, 2048, 1024);
  }
  // 7. fused highway combine + fc logits (biases applied here)
  hwfc_k<<<B_ * S_, 256, 0, stream>>>(
      (const unsigned int*)Hbf, G12, hw_Tb, hw_Hb, fc_w, fc_b, LOG);

  // 8. CRF + losses
  crf_score_k<<<B_, 256, 0, stream>>>(x, tags, LOG, cstart, cend, ctrans, score);
  crf_forward_k<<<B_, 64, 0, stream>>>(x, LOG, cstart, cend, ctrans, logz);
  nll_k<<<(B_ * S_ + 255) / 256, 256, 0, stream>>>(LOG, tags, accum);
  final_k<<<1, 64, 0, stream>>>(score, logz, accum, (float*)d_out);
}

// Round 18
// 3218.451 us; speedup vs baseline: 1.2258x; 1.0219x over previous
//
#include <hip/hip_runtime.h>
#include <math.h>

// Model dims
#define B_   32
#define S_   256
#define T_   20
#define H_   512
#define E_   300
#define C_   16
#define CE_  30
#define NF_  50
#define IN0_ 450      // E + 3*NF
#define KP0_ 480      // IN0 padded to %32
#define G4_  2048     // 4*H
#define NG_  4096     // 2 dirs * 4H

typedef __attribute__((ext_vector_type(8))) short bf16x8;
typedef __attribute__((ext_vector_type(4))) float f32x4;

__device__ __forceinline__ float sigm(float x) { return 1.f / (1.f + __expf(-x)); }
__device__ __forceinline__ float tanhfast(float x) {
  x = fminf(15.f, fmaxf(-15.f, x));
  float e = __expf(-2.f * x);
  return (1.f - e) / (1.f + e);
}
__device__ __forceinline__ unsigned short f2bf(float f) {
  unsigned int u = __float_as_uint(f);
  unsigned int r = (u + 0x7fffu + ((u >> 16) & 1u)) >> 16;
  return (unsigned short)r;
}
__device__ __forceinline__ float bf2f(unsigned int u) {
  return __uint_as_float(u << 16);
}

// direct global->LDS staging (16B/lane, wave-uniform LDS base + lane*16)
#define GLOAD_LDS(gp, lp)                                                    \
  __builtin_amdgcn_global_load_lds(                                          \
      (const __attribute__((address_space(1))) void*)(gp),                   \
      (__attribute__((address_space(3))) void*)(lp), 16, 0, 0)

// ---------------- Embedding + char CNN -> bf16 padded [8192][480] ----------------
__global__ __launch_bounds__(256) void embed_cnn(
    const int* __restrict__ x, const int* __restrict__ xc,
    const float* __restrict__ wemb, const float* __restrict__ cemb,
    const float* __restrict__ w2, const float* __restrict__ cb2,
    const float* __restrict__ w3, const float* __restrict__ cb3,
    const float* __restrict__ w4, const float* __restrict__ cb4,
    unsigned short* __restrict__ out) {
  int m = blockIdx.x;           // m = t*32 + b
  int t = m >> 5, b = m & 31;
  int tid = threadIdx.x;
  __shared__ float emb[C_][CE_];
  __shared__ float conv[2100];

  int wid = x[b * S_ + t];
  for (int e = tid; e < KP0_; e += 256) {
    if (e < E_) out[(size_t)m * KP0_ + e] = f2bf(wemb[(size_t)wid * E_ + e]);
    else if (e >= IN0_) out[(size_t)m * KP0_ + e] = 0;
  }

  for (int idx = tid; idx < C_ * CE_; idx += 256) {
    int c = idx / CE_, ce = idx % CE_;
    int cid = xc[(b * S_ + t) * C_ + c];
    emb[c][ce] = cemb[cid * CE_ + ce];
  }
  __syncthreads();

  for (int idx = tid; idx < 2100; idx += 256) {
    int kw, f, p;
    const float* w; const float* bb;
    int r = idx;
    if (r < 750)      { kw = 2; f = r / 15; p = r % 15; w = w2; bb = cb2; }
    else if (r < 1450){ r -= 750;  kw = 3; f = r / 14; p = r % 14; w = w3; bb = cb3; }
    else              { r -= 1450; kw = 4; f = r / 13; p = r % 13; w = w4; bb = cb4; }
    float acc = bb[f];
    for (int j = 0; j < kw; ++j)
      for (int ce = 0; ce < CE_; ++ce)
        acc = fmaf(emb[p + j][ce], w[(f * CE_ + ce) * kw + j], acc);
    conv[idx] = fmaxf(acc, 0.f);
  }
  __syncthreads();

  if (tid < 150) {
    int kk = tid / 50, f = tid % 50;
    int base, np;
    if (kk == 0)      { base = f * 15;        np = 15; }
    else if (kk == 1) { base = 750 + f * 14;  np = 14; }
    else              { base = 1450 + f * 13; np = 13; }
    float mx = 0.f;
    for (int p = 0; p < np; ++p) mx = fmaxf(mx, conv[base + p]);
    out[(size_t)m * KP0_ + E_ + kk * 50 + f] = f2bf(mx);
  }
}

// ---------------- fp32 -> bf16 cast with K padding ----------------
__global__ __launch_bounds__(256) void castpad(
    const float* __restrict__ src, unsigned short* __restrict__ dst,
    int R, int K, int Kp) {
  int i = blockIdx.x * 256 + threadIdx.x;
  if (i < R * Kp) {
    int r = i / Kp, k = i - r * Kp;
    dst[i] = (k < K) ? f2bf(src[(size_t)r * K + k]) : (unsigned short)0;
  }
}

// ---------------- bf16 MFMA GEMM (global_load_lds staging): C = A @ W^T + b1 + b2 ----------------
__global__ __launch_bounds__(256) void gemm_bf16(
    const unsigned short* __restrict__ A, const unsigned short* __restrict__ W,
    const float* __restrict__ bias1, const float* __restrict__ bias2,
    float* __restrict__ C, int M, int N, int Kp) {
  __shared__ unsigned short As[128][32];   // linear: row = 64B (required by gload_lds)
  __shared__ unsigned short Bs[128][32];
  int bm = blockIdx.y * 128, bn = blockIdx.x * 128;
  int tid = threadIdx.x;
  int wave = tid >> 6, lane = tid & 63;
  int wm = (wave & 1) * 64, wn = (wave >> 1) * 64;
  int l15 = lane & 15, l4 = lane >> 4;

  int srow = lane >> 2;
  int scol = (lane & 3) * 8;
  const unsigned short* ga0 = A + (size_t)(bm + wave * 32 + srow) * Kp + scol;
  const unsigned short* ga1 = A + (size_t)(bm + wave * 32 + 16 + srow) * Kp + scol;
  const unsigned short* gb0 = W + (size_t)(bn + wave * 32 + srow) * Kp + scol;
  const unsigned short* gb1 = W + (size_t)(bn + wave * 32 + 16 + srow) * Kp + scol;

  f32x4 acc[4][4];
#pragma unroll
  for (int i = 0; i < 4; ++i)
#pragma unroll
    for (int j = 0; j < 4; ++j) acc[i][j] = (f32x4){0.f, 0.f, 0.f, 0.f};

  for (int k0 = 0; k0 < Kp; k0 += 32) {
    __syncthreads();
    GLOAD_LDS(ga0 + k0, &As[wave * 32][0]);
    GLOAD_LDS(ga1 + k0, &As[wave * 32 + 16][0]);
    GLOAD_LDS(gb0 + k0, &Bs[wave * 32][0]);
    GLOAD_LDS(gb1 + k0, &Bs[wave * 32 + 16][0]);
    __syncthreads();

    bf16x8 af[4], bfv[4];
#pragma unroll
    for (int i = 0; i < 4; ++i) af[i]  = *(const bf16x8*)&As[wm + i * 16 + l15][l4 * 8];
#pragma unroll
    for (int j = 0; j < 4; ++j) bfv[j] = *(const bf16x8*)&Bs[wn + j * 16 + l15][l4 * 8];
#pragma unroll
    for (int i = 0; i < 4; ++i)
#pragma unroll
      for (int j = 0; j < 4; ++j)
        acc[i][j] = __builtin_amdgcn_mfma_f32_16x16x32_bf16(af[i], bfv[j], acc[i][j], 0, 0, 0);
  }

#pragma unroll
  for (int j = 0; j < 4; ++j) {
    int gn = bn + wn + j * 16 + l15;
    float bsum = (bias1 ? bias1[gn] : 0.f) + (bias2 ? bias2[gn] : 0.f);
#pragma unroll
    for (int i = 0; i < 4; ++i) {
#pragma unroll
      for (int r = 0; r < 4; ++r) {
        int gm = bm + wm + i * 16 + l4 * 4 + r;
        C[(size_t)gm * N + gn] = acc[i][j][r] + bsum;
      }
    }
  }
}

// ---------------- Persistent BiLSTM scan: fused gates + Hbf-as-exchange ----------------
// r17 structure (64 WGs, fused gates-in-lane), two changes:
//  (1) h stored ONCE: agent-atomic to Hbf32[t][b][dir*256+hw]. Recurrence
//      stages prior-h from Hbf32[tp] (per-timestep storage -> no parity
//      buffer, no hT, half the stores on the drain path).
//  (2) no release barrier: after the drain __syncthreads (which also covers
//      the hlds WAR), wave0-lane0 publishes the flag and EVERY wave polls
//      the 32 flags itself before issuing its stage loads.
__global__ __launch_bounds__(512, 2) void lstm_scan(
    const float* __restrict__ P,          // [8192][4096] x-proj + biases
    const float* __restrict__ whh,        // [2][2048][512]
    unsigned int* __restrict__ Hbf32,     // [8192][512] u32 = bf16 pairs (exchange + output)
    int* __restrict__ flags) {            // [2 dirs][32]
  int wg  = blockIdx.x;
  int dir = wg >> 5;
  int hb  = wg & 31;
  int tid = threadIdx.x;
  int wave = tid >> 6;
  int lane = tid & 63;
  int hq = wave >> 1;
  int nb = wave & 1;
  int l15 = lane & 15;
  int l4  = lane >> 4;
  int hidx = hb * 16 + hq * 4 + l4;       // this lane's hidden unit
  int bidx = nb * 16 + l15;               // this lane's batch element

  // resident weight A-fragments: A-row l15 <-> (hh = l15>>2, gate = l15&3)
  int arow_h = hb * 16 + hq * 4 + (l15 >> 2);
  int arow_g = l15 & 3;
  const float* wrow = whh + ((size_t)dir * G4_ + arow_g * H_ + arow_h) * H_;
  bf16x8 afrag[16];
#pragma unroll
  for (int kk = 0; kk < 16; ++kk) {
    int k0 = kk * 32 + l4 * 8;
    float4 lo = *(const float4*)(wrow + k0);
    float4 hi = *(const float4*)(wrow + k0 + 4);
    bf16x8 a;
    a[0] = (short)f2bf(lo.x); a[1] = (short)f2bf(lo.y);
    a[2] = (short)f2bf(lo.z); a[3] = (short)f2bf(lo.w);
    a[4] = (short)f2bf(hi.x); a[5] = (short)f2bf(hi.y);
    a[6] = (short)f2bf(hi.z); a[7] = (short)f2bf(hi.w);
    afrag[kk] = a;
  }

  __shared__ unsigned short hlds[32][520];   // 1040B row stride
  int* dflags = flags + dir * 32;

  float cst = 0.f;                           // cell state for (hidx, bidx)
  float pfc[4], pfn[4];                      // P per gate (i,f,g,o)

  {
    int t0i = dir ? (S_ - 1) : 0;
    size_t pr = ((size_t)(t0i * B_ + bidx)) * NG_ + (size_t)dir * G4_ + hidx;
#pragma unroll
    for (int gg = 0; gg < 4; ++gg) pfc[gg] = P[pr + gg * H_];
  }

  // staging mapping: lane stages batch row (wave*4 + (lane&3)), 64B chunk (lane>>2)
  int srow   = wave * 4 + (lane & 3);
  int schunk = lane >> 2;
  const unsigned short* Hsh = (const unsigned short*)Hbf32;  // [8192][1024] shorts

  for (int s = 0; s < S_; ++s) {
    int t = dir ? (S_ - 1 - s) : s;

    f32x4 acc = {0.f, 0.f, 0.f, 0.f};
    if (s > 0) {
      int tp = dir ? (t + 1) : (t - 1);    // prior timestep (step s-1)
      const unsigned short* src = Hsh + ((size_t)(tp * B_ + srow)) * 1024
                                  + dir * 512 + schunk * 32;
      bf16x8 t0, t1, t2, t3;
      asm volatile("global_load_dwordx4 %0, %1, off sc0 sc1"           : "=v"(t0) : "v"(src) : "memory");
      asm volatile("global_load_dwordx4 %0, %1, off offset:16 sc0 sc1" : "=v"(t1) : "v"(src) : "memory");
      asm volatile("global_load_dwordx4 %0, %1, off offset:32 sc0 sc1" : "=v"(t2) : "v"(src) : "memory");
      asm volatile("global_load_dwordx4 %0, %1, off offset:48 sc0 sc1" : "=v"(t3) : "v"(src) : "memory");
      // prefetch next step's P while stage loads are in flight; wait for the
      // STAGE loads only (4 younger P loads stay outstanding).
      if (s < S_ - 1) {
        int tn = dir ? (S_ - 2 - s) : (s + 1);
        size_t pr = ((size_t)(tn * B_ + bidx)) * NG_ + (size_t)dir * G4_ + hidx;
#pragma unroll
        for (int gg = 0; gg < 4; ++gg) pfn[gg] = P[pr + gg * H_];
        asm volatile("s_waitcnt vmcnt(4)" ::: "memory");
      } else {
        asm volatile("s_waitcnt vmcnt(0)" ::: "memory");
      }
      __builtin_amdgcn_sched_barrier(0);
      *(bf16x8*)&hlds[srow][schunk * 32 +  0] = t0;
      *(bf16x8*)&hlds[srow][schunk * 32 +  8] = t1;
      *(bf16x8*)&hlds[srow][schunk * 32 + 16] = t2;
      *(bf16x8*)&hlds[srow][schunk * 32 + 24] = t3;
      __syncthreads();   // stage visible to all waves

      bf16x8 bv[16];
#pragma unroll
      for (int kk = 0; kk < 16; ++kk)
        bv[kk] = *(const bf16x8*)&hlds[nb * 16 + l15][kk * 32 + l4 * 8];
#pragma unroll
      for (int kk = 0; kk < 16; ++kk)
        acc = __builtin_amdgcn_mfma_f32_16x16x32_bf16(afrag[kk], bv[kk], acc, 0, 0, 0);
    } else {
      // prefetch for step 1
      int tn = dir ? (S_ - 2) : 1;
      size_t pr = ((size_t)(tn * B_ + bidx)) * NG_ + (size_t)dir * G4_ + hidx;
#pragma unroll
      for (int gg = 0; gg < 4; ++gg) pfn[gg] = P[pr + gg * H_];
    }

    // pointwise, in-lane (all 8 waves): acc reg r = gate r (i,f,g,o)
    {
      float iv = acc[0] + pfc[0];
      float fv = acc[1] + pfc[1];
      float gv = acc[2] + pfc[2];
      float ov = acc[3] + pfc[3];
      cst = sigm(fv) * cst + sigm(iv) * tanhfast(gv);
      float hn = sigm(ov) * tanhfast(cst);
      // pack hidden pair (hidx even lane | hidx^1 from lane^16) into u32
      unsigned int m = (unsigned int)f2bf(hn);
      unsigned int pm = (unsigned int)__shfl_xor((int)m, 16);
      if ((l4 & 1) == 0) {
        unsigned int w = m | (pm << 16);
        int hw = hidx >> 1;                  // hb*8 + hq*2 + l4/2
        unsigned int* hc = Hbf32 + ((size_t)(t * B_ + bidx)) * 512 + dir * 256 + hw;
        __hip_atomic_store(hc, w, __ATOMIC_RELAXED, __HIP_MEMORY_SCOPE_AGENT);
      }
      // rotate P double-buffer
#pragma unroll
      for (int gg = 0; gg < 4; ++gg) pfc[gg] = pfn[gg];
    }

    if (s < S_ - 1) {
      __syncthreads();   // drains vmcnt per wave (h stores at LLC) + hlds WAR guard
      if (wave == 0 && lane == 0)
        __hip_atomic_store(dflags + hb, s + 1, __ATOMIC_RELAXED, __HIP_MEMORY_SCOPE_AGENT);
      // every wave verifies all 32 flags before its next stage loads
      {
        int target = s + 1;
        int guard = 0;
        for (;;) {
          int v = target;
          if (lane < 32)
            v = __hip_atomic_load(dflags + lane, __ATOMIC_RELAXED, __HIP_MEMORY_SCOPE_AGENT);
          if (__all(v >= target)) break;
          __builtin_amdgcn_s_sleep(1);
          if (++guard > (1 << 17)) break;   // safety valve: wrong answer, not a hang
        }
      }
    }
  }
}

// ---------------- fused highway + FC logits (one row per block) ----------------
// G12 = [8192][2048]: cols 0..1023 = T-gate pre-act (no bias), 1024..2047 = H pre-act.
__global__ __launch_bounds__(256) void hwfc_k(
    const unsigned int* __restrict__ Xbf,  // [8192][512] bf16 pairs (LSTM out)
    const float* __restrict__ G12,         // [8192][2048]
    const float* __restrict__ hw_Tb, const float* __restrict__ hw_Hb,
    const float* __restrict__ fc_w,        // [20][1024]
    const float* __restrict__ fc_b,        // [20]
    float* __restrict__ LOG) {             // [8192][20]
  int m = blockIdx.x;
  int tid = threadIdx.x;
  int wave = tid >> 6, lane = tid & 63;
  int e0 = tid * 4;

  unsigned int xv0 = Xbf[(size_t)m * 512 + tid * 2];
  unsigned int xv1 = Xbf[(size_t)m * 512 + tid * 2 + 1];
  float4 g1 = *(const float4*)(G12 + (size_t)m * 2048 + e0);
  float4 g2 = *(const float4*)(G12 + (size_t)m * 2048 + 1024 + e0);
  float4 tb = *(const float4*)(hw_Tb + e0);
  float4 hbv = *(const float4*)(hw_Hb + e0);
  g1.x += tb.x; g1.y += tb.y; g1.z += tb.z; g1.w += tb.w;
  g2.x += hbv.x; g2.y += hbv.y; g2.z += hbv.z; g2.w += hbv.w;
  float tg, o[4];
  tg = sigm(g1.x); o[0] = tg * fmaxf(g2.x, 0.f) + (1.f - tg) * bf2f(xv0 & 0xffffu);
  tg = sigm(g1.y); o[1] = tg * fmaxf(g2.y, 0.f) + (1.f - tg) * bf2f(xv0 >> 16);
  tg = sigm(g1.z); o[2] = tg * fmaxf(g2.z, 0.f) + (1.f - tg) * bf2f(xv1 & 0xffffu);
  tg = sigm(g1.w); o[3] = tg * fmaxf(g2.w, 0.f) + (1.f - tg) * bf2f(xv1 >> 16);

  float acc[T_];
#pragma unroll
  for (int j = 0; j < T_; ++j) {
    float4 w = *(const float4*)(fc_w + (size_t)j * 1024 + e0);
    acc[j] = o[0] * w.x + o[1] * w.y + o[2] * w.z + o[3] * w.w;
  }
#pragma unroll
  for (int off = 32; off > 0; off >>= 1)
#pragma unroll
    for (int j = 0; j < T_; ++j)
      acc[j] += __shfl_xor(acc[j], off);

  __shared__ float part[4][T_];
  if (lane == 0)
#pragma unroll
    for (int j = 0; j < T_; ++j) part[wave][j] = acc[j];
  __syncthreads();
  if (tid < T_)
    LOG[(size_t)m * T_ + tid] =
        part[0][tid] + part[1][tid] + part[2][tid] + part[3][tid] + fc_b[tid];
}

// ---------------- CRF gold score (parallel reduction over t) ----------------
__global__ __launch_bounds__(256) void crf_score_k(
    const int* __restrict__ x, const int* __restrict__ tags,
    const float* __restrict__ L,
    const float* __restrict__ cstart, const float* __restrict__ cend,
    const float* __restrict__ ctrans, float* __restrict__ score) {
  int b = blockIdx.x;
  int t = threadIdx.x;                   // S_ == 256 == blockDim
  int tg = tags[b * S_ + t];
  float part = 0.f;
  bool valid;
  if (t == 0) {
    part = cstart[tg] + L[(size_t)b * T_ + tg];
    valid = true;
  } else {
    valid = (x[b * S_ + t] != 0);
    if (valid)
      part = ctrans[tags[b * S_ + t - 1] * T_ + tg] + L[((size_t)t * B_ + b) * T_ + tg];
  }
  bool nextInvalid = (t == S_ - 1) || (x[b * S_ + t + 1] == 0);
  if (valid && nextInvalid) part += cend[tg];

  __shared__ float red[256];
  red[t] = part;
  __syncthreads();
  for (int off = 128; off > 0; off >>= 1) {
    if (t < off) red[t] += red[t + off];
    __syncthreads();
  }
  if (t == 0) score[b] = red[0];
}

// ---------------- CRF forward (log partition), one block per batch ----------------
__global__ __launch_bounds__(64) void crf_forward_k(
    const int* __restrict__ x, const float* __restrict__ L,
    const float* __restrict__ cstart, const float* __restrict__ cend,
    const float* __restrict__ ctrans, float* __restrict__ logz) {
  int b = blockIdx.x;
  int tp = threadIdx.x;
  __shared__ float alpha[T_];
  __shared__ float trT[T_][T_];
  for (int i = tp; i < T_ * T_; i += 64)
    trT[i / T_][i % T_] = ctrans[(i % T_) * T_ + (i / T_)];
  if (tp < T_) alpha[tp] = cstart[tp] + L[(size_t)b * T_ + tp];
  __syncthreads();
  for (int t = 1; t < S_; ++t) {
    float newv = 0.f;
    bool active = tp < T_;
    bool msk = x[b * S_ + t] != 0;
    if (active) {
      float em = L[((size_t)t * B_ + b) * T_ + tp];
      float mx = -1e30f;
#pragma unroll
      for (int tt = 0; tt < T_; ++tt) mx = fmaxf(mx, alpha[tt] + trT[tp][tt]);
      float sum = 0.f;
#pragma unroll
      for (int tt = 0; tt < T_; ++tt) sum += __expf(alpha[tt] + trT[tp][tt] - mx);
      float nxt = mx + __logf(sum) + em;
      newv = msk ? nxt : alpha[tp];
    }
    __syncthreads();
    if (active) alpha[tp] = newv;
    __syncthreads();
  }
  if (tp == 0) {
    float mx = -1e30f;
    for (int tt = 0; tt < T_; ++tt) mx = fmaxf(mx, alpha[tt] + cend[tt]);
    float sum = 0.f;
    for (int tt = 0; tt < T_; ++tt) sum += __expf(alpha[tt] + cend[tt] - mx);
    logz[b] = mx + __logf(sum);
  }
}

// ---------------- token NLL (aux loss) ----------------
__global__ __launch_bounds__(256) void nll_k(const float* __restrict__ L,
                                             const int* __restrict__ tags,
                                             float* __restrict__ accum) {
  int m = blockIdx.x * 256 + threadIdx.x;
  float nv = 0.f, vv = 0.f;
  if (m < B_ * S_) {
    int t = m >> 5, b = m & 31;
    int tg = tags[b * S_ + t];
    const float* row = L + (size_t)m * T_;
    float mx = -1e30f;
    for (int i = 0; i < T_; ++i) mx = fmaxf(mx, row[i]);
    float sum = 0.f;
    for (int i = 0; i < T_; ++i) sum += expf(row[i] - mx);
    float lse = mx + logf(sum);
    if (tg != 0) { nv = lse - row[tg]; vv = 1.f; }
  }
  __shared__ float sn[256], sv[256];
  int tid = threadIdx.x;
  sn[tid] = nv; sv[tid] = vv;
  __syncthreads();
  for (int off = 128; off > 0; off >>= 1) {
    if (tid < off) { sn[tid] += sn[tid + off]; sv[tid] += sv[tid + off]; }
    __syncthreads();
  }
  if (tid == 0) { atomicAdd(&accum[0], sn[0]); atomicAdd(&accum[1], sv[0]); }
}

// ---------------- final scalar ----------------
__global__ void final_k(const float* __restrict__ score, const float* __restrict__ logz,
                        const float* __restrict__ accum, float* __restrict__ out) {
  if (threadIdx.x == 0 && blockIdx.x == 0) {
    float s = 0.f;
    for (int b = 0; b < B_; ++b) s += score[b] - logz[b];
    float crf = -s / (float)B_;
    out[0] = crf + 0.1f * (accum[0] / accum[1]);
  }
}

extern "C" void kernel_launch(void* const* d_in, const int* in_sizes, int n_in,
                              void* d_out, int out_size, void* d_ws, size_t ws_size,
                              hipStream_t stream) {
  (void)in_sizes; (void)n_in; (void)out_size; (void)ws_size;
  const int*   x      = (const int*)d_in[0];
  const int*   xc     = (const int*)d_in[1];
  const int*   tags   = (const int*)d_in[2];
  const float* wemb   = (const float*)d_in[3];
  const float* cemb   = (const float*)d_in[4];
  const float* w2     = (const float*)d_in[5];
  const float* cb2    = (const float*)d_in[6];
  const float* w3     = (const float*)d_in[7];
  const float* cb3    = (const float*)d_in[8];
  const float* w4     = (const float*)d_in[9];
  const float* cb4    = (const float*)d_in[10];
  const float* l0_wih = (const float*)d_in[11];
  const float* l0_whh = (const float*)d_in[12];
  const float* l0_bih = (const float*)d_in[13];
  const float* l0_bhh = (const float*)d_in[14];
  const float* l1_wih = (const float*)d_in[15];
  const float* l1_whh = (const float*)d_in[16];
  const float* l1_bih = (const float*)d_in[17];
  const float* l1_bhh = (const float*)d_in[18];
  const float* hw_Hw  = (const float*)d_in[19];
  const float* hw_Hb  = (const float*)d_in[20];
  const float* hw_Tw  = (const float*)d_in[21];
  const float* hw_Tb  = (const float*)d_in[22];
  const float* fc_w   = (const float*)d_in[23];
  const float* fc_b   = (const float*)d_in[24];
  const float* cstart = (const float*)d_in[25];
  const float* cend   = (const float*)d_in[26];
  const float* ctrans = (const float*)d_in[27];

  // workspace layout (float units), total ~42.01M floats ~= 168 MB
  float* ws    = (float*)d_ws;
  float* P     = ws;                              // [0, 33554432)
  float* G12   = P;                               // alias (P dead after scans): 8192*2048
  unsigned short* Hbf    = (unsigned short*)(ws + 33554432);   // 8192*1024 bf16
  unsigned short* COMBbf = (unsigned short*)(ws + 37748736);   // 8192*480 bf16
  unsigned short* Wbf    = (unsigned short*)(ws + 39714816);   // 4096*1024 bf16
  float* LOG   = ws + 41811968;                   // 163,840
  int*   flags = (int*)(ws + 42008576);           // 128 ints
  float* score = ws + 42008576 + 128;
  float* logz  = score + 32;
  float* accum = logz + 32;

  hipMemsetAsync(accum, 0, 2 * sizeof(float), stream);

  // 1. embedding + char CNN -> bf16 padded
  embed_cnn<<<B_ * S_, 256, 0, stream>>>(x, xc, wemb, cemb, w2, cb2, w3, cb3, w4, cb4, COMBbf);

  // 2. layer0 input projection (bf16 MFMA)
  castpad<<<(4096 * KP0_ + 255) / 256, 256, 0, stream>>>(l0_wih, Wbf, 4096, IN0_, KP0_);
  {
    dim3 g(NG_ / 128, (B_ * S_) / 128);
    gemm_bf16<<<g, 256, 0, stream>>>(COMBbf, Wbf, l0_bih, l0_bhh, P, B_ * S_, NG_, KP0_);
  }
  // 3. layer0 recurrence
  hipMemsetAsync(flags, 0, 128 * sizeof(int), stream);
  lstm_scan<<<64, 512, 0, stream>>>(P, l0_whh, (unsigned int*)Hbf, flags);

  // 4. layer1 input projection
  castpad<<<(4096 * 1024 + 255) / 256, 256, 0, stream>>>(l1_wih, Wbf, 4096, 1024, 1024);
  {
    dim3 g(NG_ / 128, (B_ * S_) / 128);
    gemm_bf16<<<g, 256, 0, stream>>>(Hbf, Wbf, l1_bih, l1_bhh, P, B_ * S_, NG_, 1024);
  }
  // 5. layer1 recurrence
  hipMemsetAsync(flags, 0, 128 * sizeof(int), stream);
  lstm_scan<<<64, 512, 0, stream>>>(P, l1_whh, (unsigned int*)Hbf, flags);

  // 6. fused highway gate GEMM: W = [hw_Tw ; hw_Hw] (2048 x 1024), one pass over A
  castpad<<<(1024 * 1024 + 255) / 256, 256, 0, stream>>>(hw_Tw, Wbf, 1024, 1024, 1024);
  castpad<<<(1024 * 1024 + 255) / 256, 256, 0, stream>>>(hw_Hw, Wbf + 1024 * 1024, 1024, 1024, 1024);
  {
    dim3 g(2048 / 128, (B_ * S_) / 128);
    gemm_bf16<<<g, 256, 0, stream>>>(Hbf, Wbf, nullptr, nullptr, G12, B_ * S_, 2048, 1024);
  }
  // 7. fused highway combine + fc logits (biases applied here)
  hwfc_k<<<B_ * S_, 256, 0, stream>>>(
      (const unsigned int*)Hbf, G12, hw_Tb, hw_Hb, fc_w, fc_b, LOG);

  // 8. CRF + losses
  crf_score_k<<<B_, 256, 0, stream>>>(x, tags, LOG, cstart, cend, ctrans, score);
  crf_forward_k<<<B_, 64, 0, stream>>>(x, LOG, cstart, cend, ctrans, logz);
  nll_k<<<(B_ * S_ + 255) / 256, 256, 0, stream>>>(LOG, tags, accum);
  final_k<<<1, 64, 0, stream>>>(score, logz, accum, (float*)d_out);
}